// Round 1
// baseline (9737.292 us; speedup 1.0000x reference)
//
#include <hip/hip_runtime.h>
#include <hip/hip_bf16.h>
#include <math.h>

#define NH 16
#define T_ 2048
#define B_ 2
#define D_ 1024
#define EPS 1e-6f

__device__ __forceinline__ float wred_sum(float v){
  #pragma unroll
  for (int o = 32; o > 0; o >>= 1) v += __shfl_xor(v, o, 64);
  return v;
}
__device__ __forceinline__ float wred_max(float v){
  #pragma unroll
  for (int o = 32; o > 0; o >>= 1) v = fmaxf(v, __shfl_xor(v, o, 64));
  return v;
}

// C[m,n] = sum_k A[m,k] * W[n,k].  A: M x K row-major, W: N x K row-major.
// Requires M % BM == 0, K % BK == 0 (true for all our shapes); N bounds handled.
template<int BM, int BN, int BK>
__global__ void gemm_nt(const float* __restrict__ A, const float* __restrict__ W,
                        float* __restrict__ C, int M, int N, int K)
{
  __shared__ float As[BK][BM + 4];
  __shared__ float Ws[BK][BN + 4];
  const int bm = blockIdx.y * BM, bn = blockIdx.x * BN;
  const int tid = threadIdx.x;          // 256 threads
  const int tx = tid & 15, ty = tid >> 4;
  const int arow = tid >> 2;            // 0..63
  const int akk  = (tid & 3) << 2;      // 0,4,8,12
  float acc[4][4] = {{0.f}};
  for (int k0 = 0; k0 < K; k0 += BK) {
    float4 av = *(const float4*)&A[(size_t)(bm + arow) * K + k0 + akk];
    As[akk+0][arow] = av.x; As[akk+1][arow] = av.y;
    As[akk+2][arow] = av.z; As[akk+3][arow] = av.w;
    float4 wv = make_float4(0.f, 0.f, 0.f, 0.f);
    if (bn + arow < N) wv = *(const float4*)&W[(size_t)(bn + arow) * K + k0 + akk];
    Ws[akk+0][arow] = wv.x; Ws[akk+1][arow] = wv.y;
    Ws[akk+2][arow] = wv.z; Ws[akk+3][arow] = wv.w;
    __syncthreads();
    #pragma unroll
    for (int kk = 0; kk < BK; kk++) {
      float a[4], b[4];
      #pragma unroll
      for (int i = 0; i < 4; i++) a[i] = As[kk][ty*4 + i];
      #pragma unroll
      for (int j = 0; j < 4; j++) b[j] = Ws[kk][tx*4 + j];
      #pragma unroll
      for (int i = 0; i < 4; i++)
        #pragma unroll
        for (int j = 0; j < 4; j++)
          acc[i][j] = fmaf(a[i], b[j], acc[i][j]);
    }
    __syncthreads();
  }
  #pragma unroll
  for (int i = 0; i < 4; i++) {
    const int m = bm + ty*4 + i;
    #pragma unroll
    for (int j = 0; j < 4; j++) {
      const int n = bn + tx*4 + j;
      if (n < N) C[(size_t)m * N + n] = acc[i][j];
    }
  }
}

// Per (b,t,h): RMSNorm over 64 dims, *q_norm_w, then RoPE on dims 48..63. In place.
__global__ void prep_q(float* __restrict__ q, const float* __restrict__ qw,
                       const float* __restrict__ cosp, const float* __restrict__ sinp)
{
  const int lane = threadIdx.x;          // 0..63
  const int bth = blockIdx.x;            // (b*T + t)*NH + h
  const int t = (bth / NH) % T_;
  const size_t base = (size_t)bth * 64;
  float v = q[base + lane];
  const float ss = wred_sum(v * v);
  const float norm = rsqrtf(ss * (1.0f/64.0f) + EPS);
  v = v * norm * qw[lane];
  const float partner = __shfl_xor(v, 8, 64);   // pairs 48..55 <-> 56..63
  if (lane >= 48) {
    const int j = lane & 7;
    const float c = cosp[t*8 + j], s = sinp[t*8 + j];
    v = (lane < 56) ? (v * c - partner * s)     // x1*cos - x2*sin
                    : (v * c + partner * s);    // x2*cos + x1*sin
  }
  q[base + lane] = v;
}

// Per (b,t): RMSNorm over kv_a[:128] -> kvl; RoPE on kv_a[128:144] -> krope.
__global__ void prep_kv(const float* __restrict__ kva, const float* __restrict__ kw,
                        const float* __restrict__ cosp, const float* __restrict__ sinp,
                        float* __restrict__ kvl, float* __restrict__ krope)
{
  const int tid = threadIdx.x;   // 0..127
  const int bt = blockIdx.x;     // 0..B*T-1
  const int t = bt % T_;
  const float* row = kva + (size_t)bt * 144;
  const float v = row[tid];
  float s = wred_sum(v * v);
  __shared__ float red[2];
  if ((tid & 63) == 0) red[tid >> 6] = s;
  __syncthreads();
  const float total = red[0] + red[1];
  const float norm = rsqrtf(total * (1.0f/128.0f) + EPS);
  kvl[(size_t)bt * 128 + tid] = v * norm * kw[tid];
  if (tid < 16) {
    const int j = tid & 7;
    const float c = cosp[t*8 + j], sn = sinp[t*8 + j];
    const float x1 = row[128 + j], x2 = row[136 + j];
    krope[(size_t)bt * 16 + tid] = (tid < 8) ? (x1 * c - x2 * sn)
                                             : (x2 * c + x1 * sn);
  }
}

// One wave per query row (b, h, qt). K staged in LDS (padded, conflict-free),
// scores in LDS p[], two-pass softmax, coalesced V accumulation.
__global__ void attn(const float* __restrict__ q, const float* __restrict__ kvb,
                     const float* __restrict__ krope, float* __restrict__ aout)
{
  const int lane = threadIdx.x;          // 0..63
  const int qt = blockIdx.x;
  const int bh = blockIdx.y;
  const int b = bh >> 4, h = bh & 15;
  __shared__ float qv[64];
  __shared__ float Kt[64][65];
  __shared__ float p[T_];
  const size_t qoff = ((size_t)(b*T_ + qt) * NH + h) * 64;
  qv[lane] = q[qoff + lane];
  __syncthreads();

  float mmax = -1e30f;
  const int ntile = (qt >> 6) + 1;
  const size_t hoff = (size_t)h * 112;
  for (int kt = 0; kt < ntile; kt++) {
    const int kbase = kt << 6;
    for (int r = 0; r < 64; r++) {
      const int k = kbase + r;
      float val = 0.f;
      if (k <= qt) {
        val = (lane < 48) ? kvb[(size_t)(b*T_ + k) * 1792 + hoff + lane]
                          : krope[(size_t)(b*T_ + k) * 16 + (lane - 48)];
      }
      Kt[r][lane] = val;
    }
    __syncthreads();
    const int k = kbase + lane;
    if (k <= qt) {
      float s = 0.f;
      #pragma unroll
      for (int d = 0; d < 64; d++) s = fmaf(qv[d], Kt[lane][d], s);
      s *= 0.125f;                      // (NOPE_D+ROPE_D)^-0.5 = 1/8
      p[k] = s;
      mmax = fmaxf(mmax, s);
    }
    __syncthreads();
  }
  mmax = wred_max(mmax);
  float lsum = 0.f;
  for (int k = lane; k <= qt; k += 64) {
    const float e = __expf(p[k] - mmax);
    p[k] = e;
    lsum += e;
  }
  lsum = wred_sum(lsum);
  __syncthreads();

  float o = 0.f;
  const float* vp = kvb + (size_t)b * T_ * 1792 + hoff + 48 + lane;
  #pragma unroll 4
  for (int k = 0; k <= qt; k++) o = fmaf(p[k], vp[(size_t)k * 1792], o);
  o *= (1.0f / lsum);
  aout[(size_t)(b*T_ + qt) * 1024 + h*64 + lane] = o;
}

extern "C" void kernel_launch(void* const* d_in, const int* in_sizes, int n_in,
                              void* d_out, int out_size, void* d_ws, size_t ws_size,
                              hipStream_t stream)
{
  const float* x    = (const float*)d_in[0];
  const float* cosp = (const float*)d_in[1];
  const float* sinp = (const float*)d_in[2];
  const float* Wq   = (const float*)d_in[3];
  const float* qw   = (const float*)d_in[4];
  const float* Wkva = (const float*)d_in[5];
  const float* kw   = (const float*)d_in[6];
  const float* Wkvb = (const float*)d_in[7];
  const float* Wo   = (const float*)d_in[8];
  float* out = (float*)d_out;

  float* ws    = (float*)d_ws;
  float* q     = ws;                    // B*T*NH*64      = 4,194,304 f
  float* kva   = q     + 4194304;       // B*T*144        =   589,824 f
  float* kvl   = kva   + 589824;        // B*T*128        =   524,288 f
  float* krope = kvl   + 524288;        // B*T*16         =    65,536 f
  float* kvb   = krope + 65536;         // B*T*1792       = 7,340,032 f
  float* aout  = kvb   + 7340032;       // B*T*1024       = 4,194,304 f

  const int M = B_ * T_;                // 4096

  // q = x @ Wq^T   (4096 x 1024 x 1024)
  gemm_nt<64,64,16><<<dim3(1024/64, M/64), 256, 0, stream>>>(x, Wq, q, M, 1024, 1024);
  // kv_a = x @ Wkva^T  (4096 x 144 x 1024)
  gemm_nt<64,64,16><<<dim3(3, M/64), 256, 0, stream>>>(x, Wkva, kva, M, 144, 1024);
  // RMSNorm + RoPE
  prep_q<<<M * NH, 64, 0, stream>>>(q, qw, cosp, sinp);
  prep_kv<<<M, 128, 0, stream>>>(kva, kw, cosp, sinp, kvl, krope);
  // kv_b = kv_latent @ Wkvb^T  (4096 x 1792 x 128)
  gemm_nt<64,64,16><<<dim3(1792/64, M/64), 256, 0, stream>>>(kvl, Wkvb, kvb, M, 1792, 128);
  // causal attention
  attn<<<dim3(T_, B_ * NH), 64, 0, stream>>>(q, kvb, krope, aout);
  // out = aout @ Wo^T  (4096 x 1024 x 1024)
  gemm_nt<64,64,16><<<dim3(1024/64, M/64), 256, 0, stream>>>(aout, Wo, out, M, 1024, 1024);
}

// Round 2
// 1224.739 us; speedup vs baseline: 7.9505x; 7.9505x over previous
//
#include <hip/hip_runtime.h>
#include <hip/hip_bf16.h>
#include <math.h>

#define NH 16
#define T_ 2048
#define B_ 2
#define D_ 1024
#define EPS 1e-6f

__device__ __forceinline__ float wred_sum(float v){
  #pragma unroll
  for (int o = 32; o > 0; o >>= 1) v += __shfl_xor(v, o, 64);
  return v;
}

// C[m,n] = sum_k A[m,k] * W[n,k].  A: M x K row-major, W: N x K row-major.
template<int BM, int BN, int BK>
__global__ void gemm_nt(const float* __restrict__ A, const float* __restrict__ W,
                        float* __restrict__ C, int M, int N, int K)
{
  __shared__ float As[BK][BM + 4];
  __shared__ float Ws[BK][BN + 4];
  const int bm = blockIdx.y * BM, bn = blockIdx.x * BN;
  const int tid = threadIdx.x;          // 256 threads
  const int tx = tid & 15, ty = tid >> 4;
  const int arow = tid >> 2;            // 0..63
  const int akk  = (tid & 3) << 2;      // 0,4,8,12
  float acc[4][4] = {{0.f}};
  for (int k0 = 0; k0 < K; k0 += BK) {
    float4 av = *(const float4*)&A[(size_t)(bm + arow) * K + k0 + akk];
    As[akk+0][arow] = av.x; As[akk+1][arow] = av.y;
    As[akk+2][arow] = av.z; As[akk+3][arow] = av.w;
    float4 wv = make_float4(0.f, 0.f, 0.f, 0.f);
    if (bn + arow < N) wv = *(const float4*)&W[(size_t)(bn + arow) * K + k0 + akk];
    Ws[akk+0][arow] = wv.x; Ws[akk+1][arow] = wv.y;
    Ws[akk+2][arow] = wv.z; Ws[akk+3][arow] = wv.w;
    __syncthreads();
    #pragma unroll
    for (int kk = 0; kk < BK; kk++) {
      float a[4], b[4];
      #pragma unroll
      for (int i = 0; i < 4; i++) a[i] = As[kk][ty*4 + i];
      #pragma unroll
      for (int j = 0; j < 4; j++) b[j] = Ws[kk][tx*4 + j];
      #pragma unroll
      for (int i = 0; i < 4; i++)
        #pragma unroll
        for (int j = 0; j < 4; j++)
          acc[i][j] = fmaf(a[i], b[j], acc[i][j]);
    }
    __syncthreads();
  }
  #pragma unroll
  for (int i = 0; i < 4; i++) {
    const int m = bm + ty*4 + i;
    #pragma unroll
    for (int j = 0; j < 4; j++) {
      const int n = bn + tx*4 + j;
      if (n < N) C[(size_t)m * N + n] = acc[i][j];
    }
  }
}

// Per (b,t,h): RMSNorm over 64 dims, *q_norm_w, then RoPE on dims 48..63. In place.
__global__ void prep_q(float* __restrict__ q, const float* __restrict__ qw,
                       const float* __restrict__ cosp, const float* __restrict__ sinp)
{
  const int lane = threadIdx.x;          // 0..63
  const int bth = blockIdx.x;            // (b*T + t)*NH + h
  const int t = (bth / NH) % T_;
  const size_t base = (size_t)bth * 64;
  float v = q[base + lane];
  const float ss = wred_sum(v * v);
  const float norm = rsqrtf(ss * (1.0f/64.0f) + EPS);
  v = v * norm * qw[lane];
  const float partner = __shfl_xor(v, 8, 64);   // pairs 48..55 <-> 56..63
  if (lane >= 48) {
    const int j = lane & 7;
    const float c = cosp[t*8 + j], s = sinp[t*8 + j];
    v = (lane < 56) ? (v * c - partner * s)
                    : (v * c + partner * s);
  }
  q[base + lane] = v;
}

// Per (b,t): RMSNorm over kv_a[:128] -> kvl; RoPE on kv_a[128:144] -> krope.
__global__ void prep_kv(const float* __restrict__ kva, const float* __restrict__ kw,
                        const float* __restrict__ cosp, const float* __restrict__ sinp,
                        float* __restrict__ kvl, float* __restrict__ krope)
{
  const int tid = threadIdx.x;   // 0..127
  const int bt = blockIdx.x;     // 0..B*T-1
  const int t = bt % T_;
  const float* row = kva + (size_t)bt * 144;
  const float v = row[tid];
  float s = wred_sum(v * v);
  __shared__ float red[2];
  if ((tid & 63) == 0) red[tid >> 6] = s;
  __syncthreads();
  const float total = red[0] + red[1];
  const float norm = rsqrtf(total * (1.0f/128.0f) + EPS);
  kvl[(size_t)bt * 128 + tid] = v * norm * kw[tid];
  if (tid < 16) {
    const int j = tid & 7;
    const float c = cosp[t*8 + j], sn = sinp[t*8 + j];
    const float x1 = row[128 + j], x2 = row[136 + j];
    krope[(size_t)bt * 16 + tid] = (tid < 8) ? (x1 * c - x2 * sn)
                                             : (x2 * c + x1 * sn);
  }
}

// Flash attention: one block per (b,h,64-query tile). 256 threads, 4x4 register
// tiling for QK^T and PV, K/V/Q/P in LDS with LD=65 (bank=(row+col)%32: all hot
// read patterns <=2-way aliased = free). Online softmax, 16-lane segment reduce.
__global__ __launch_bounds__(256)
void attn_flash(const float* __restrict__ q, const float* __restrict__ kvb,
                const float* __restrict__ krope, float* __restrict__ aout)
{
  __shared__ float Qs[64][65];
  __shared__ float Ks[64][65];
  __shared__ float Vs[64][65];
  __shared__ float Ps[64][65];
  const int tid = threadIdx.x;
  const int tx = tid & 15, ty = tid >> 4;      // ty group = 16 consecutive lanes
  const int qt0 = blockIdx.x * 64;
  const int bh = blockIdx.y;
  const int b = bh >> 4, h = bh & 15;
  const size_t hoff = (size_t)h * 112;

  // Load+scale Q tile: 64 rows x 64 cols, scale by 1/8 here.
  #pragma unroll
  for (int i = 0; i < 4; i++) {
    const int idx = tid + i * 256;
    const int row = idx >> 4;
    const int c4 = (idx & 15) * 4;
    float4 v = *(const float4*)&q[((size_t)(b*T_ + qt0 + row) * NH + h) * 64 + c4];
    Qs[row][c4+0] = v.x * 0.125f; Qs[row][c4+1] = v.y * 0.125f;
    Qs[row][c4+2] = v.z * 0.125f; Qs[row][c4+3] = v.w * 0.125f;
  }

  float m[4], l[4], acc[4][4];
  #pragma unroll
  for (int i = 0; i < 4; i++) {
    m[i] = -1e30f; l[i] = 0.f;
    #pragma unroll
    for (int j = 0; j < 4; j++) acc[i][j] = 0.f;
  }

  const int srow = tid >> 2;          // staging row 0..63
  const int sq   = tid & 3;           // staging quarter (16 cols)

  for (int kbase = 0; kbase <= qt0; kbase += 64) {
    // ---- stage K and V tiles ----
    {
      const int k = kbase + srow;
      const size_t rb = (size_t)(b*T_ + k);
      const float* ksrc = (sq < 3) ? &kvb[rb * 1792 + hoff + sq*16]
                                   : &krope[rb * 16];
      const float* vsrc = &kvb[rb * 1792 + hoff + 48 + sq*16];
      #pragma unroll
      for (int c = 0; c < 4; c++) {
        float4 kv4 = *(const float4*)(ksrc + c*4);
        const int col = sq*16 + c*4;
        Ks[srow][col+0] = kv4.x; Ks[srow][col+1] = kv4.y;
        Ks[srow][col+2] = kv4.z; Ks[srow][col+3] = kv4.w;
        float4 vv4 = *(const float4*)(vsrc + c*4);
        Vs[srow][col+0] = vv4.x; Vs[srow][col+1] = vv4.y;
        Vs[srow][col+2] = vv4.z; Vs[srow][col+3] = vv4.w;
      }
    }
    __syncthreads();

    // ---- S = Q K^T (scaled) ----
    float s[4][4] = {{0.f}};
    #pragma unroll 8
    for (int d = 0; d < 64; d++) {
      float a[4], bv[4];
      #pragma unroll
      for (int i = 0; i < 4; i++) a[i] = Qs[ty*4 + i][d];
      #pragma unroll
      for (int j = 0; j < 4; j++) bv[j] = Ks[tx*4 + j][d];
      #pragma unroll
      for (int i = 0; i < 4; i++)
        #pragma unroll
        for (int j = 0; j < 4; j++)
          s[i][j] = fmaf(a[i], bv[j], s[i][j]);
    }

    // ---- causal mask (diagonal tile only) ----
    if (kbase == qt0) {
      #pragma unroll
      for (int i = 0; i < 4; i++)
        #pragma unroll
        for (int j = 0; j < 4; j++)
          if (tx*4 + j > ty*4 + i) s[i][j] = -1e30f;
    }

    // ---- online softmax, write P ----
    #pragma unroll
    for (int i = 0; i < 4; i++) {
      float mr = fmaxf(fmaxf(s[i][0], s[i][1]), fmaxf(s[i][2], s[i][3]));
      #pragma unroll
      for (int o = 1; o < 16; o <<= 1) mr = fmaxf(mr, __shfl_xor(mr, o, 64));
      const float mn = fmaxf(m[i], mr);
      const float alpha = __expf(m[i] - mn);
      float rs = 0.f;
      #pragma unroll
      for (int j = 0; j < 4; j++) {
        const float p = __expf(s[i][j] - mn);
        Ps[ty*4 + i][tx*4 + j] = p;
        rs += p;
      }
      #pragma unroll
      for (int o = 1; o < 16; o <<= 1) rs += __shfl_xor(rs, o, 64);
      l[i] = l[i] * alpha + rs;
      m[i] = mn;
      #pragma unroll
      for (int j = 0; j < 4; j++) acc[i][j] *= alpha;
    }
    __syncthreads();

    // ---- acc += P V ----
    #pragma unroll 8
    for (int k = 0; k < 64; k++) {
      float a[4], bv[4];
      #pragma unroll
      for (int i = 0; i < 4; i++) a[i] = Ps[ty*4 + i][k];
      #pragma unroll
      for (int j = 0; j < 4; j++) bv[j] = Vs[k][tx*4 + j];
      #pragma unroll
      for (int i = 0; i < 4; i++)
        #pragma unroll
        for (int j = 0; j < 4; j++)
          acc[i][j] = fmaf(a[i], bv[j], acc[i][j]);
    }
    __syncthreads();
  }

  // ---- epilogue: normalize, store ----
  #pragma unroll
  for (int i = 0; i < 4; i++) {
    const float inv = 1.0f / l[i];
    const int row = qt0 + ty*4 + i;
    #pragma unroll
    for (int j = 0; j < 4; j++)
      aout[(size_t)(b*T_ + row) * 1024 + h*64 + tx*4 + j] = acc[i][j] * inv;
  }
}

extern "C" void kernel_launch(void* const* d_in, const int* in_sizes, int n_in,
                              void* d_out, int out_size, void* d_ws, size_t ws_size,
                              hipStream_t stream)
{
  const float* x    = (const float*)d_in[0];
  const float* cosp = (const float*)d_in[1];
  const float* sinp = (const float*)d_in[2];
  const float* Wq   = (const float*)d_in[3];
  const float* qw   = (const float*)d_in[4];
  const float* Wkva = (const float*)d_in[5];
  const float* kw   = (const float*)d_in[6];
  const float* Wkvb = (const float*)d_in[7];
  const float* Wo   = (const float*)d_in[8];
  float* out = (float*)d_out;

  float* ws    = (float*)d_ws;
  float* q     = ws;                    // B*T*NH*64      = 4,194,304 f
  float* kva   = q     + 4194304;       // B*T*144        =   589,824 f
  float* kvl   = kva   + 589824;        // B*T*128        =   524,288 f
  float* krope = kvl   + 524288;        // B*T*16         =    65,536 f
  float* kvb   = krope + 65536;         // B*T*1792       = 7,340,032 f
  float* aout  = kvb   + 7340032;       // B*T*1024       = 4,194,304 f

  const int M = B_ * T_;                // 4096

  gemm_nt<64,64,16><<<dim3(1024/64, M/64), 256, 0, stream>>>(x, Wq, q, M, 1024, 1024);
  gemm_nt<64,64,16><<<dim3(3, M/64), 256, 0, stream>>>(x, Wkva, kva, M, 144, 1024);
  prep_q<<<M * NH, 64, 0, stream>>>(q, qw, cosp, sinp);
  prep_kv<<<M, 128, 0, stream>>>(kva, kw, cosp, sinp, kvl, krope);
  gemm_nt<64,64,16><<<dim3(1792/64, M/64), 256, 0, stream>>>(kvl, Wkvb, kvb, M, 1792, 128);
  attn_flash<<<dim3(T_/64, B_ * NH), 256, 0, stream>>>(q, kvb, krope, aout);
  gemm_nt<64,64,16><<<dim3(1024/64, M/64), 256, 0, stream>>>(aout, Wo, out, M, 1024, 1024);
}

// Round 3
// 677.583 us; speedup vs baseline: 14.3706x; 1.8075x over previous
//
#include <hip/hip_runtime.h>
#include <hip/hip_bf16.h>
#include <math.h>

#define NH 16
#define T_ 2048
#define B_ 2
#define D_ 1024
#define EPS 1e-6f

typedef __attribute__((ext_vector_type(8))) short bf16x8;
typedef __attribute__((ext_vector_type(4))) float f32x4;

__device__ __forceinline__ float wred_sum(float v){
  #pragma unroll
  for (int o = 32; o > 0; o >>= 1) v += __shfl_xor(v, o, 64);
  return v;
}

__device__ __forceinline__ unsigned pack_bf16(float a, float b){
  __hip_bfloat162 t = __float22bfloat162_rn(make_float2(a, b));
  unsigned r; __builtin_memcpy(&r, &t, 4); return r;
}

// C[m,n] = sum_k A[m,k] * W[n,k].  A: M x K row-major, W: N x K row-major.
template<int BM, int BN, int BK>
__global__ void gemm_nt(const float* __restrict__ A, const float* __restrict__ W,
                        float* __restrict__ C, int M, int N, int K)
{
  __shared__ float As[BK][BM + 4];
  __shared__ float Ws[BK][BN + 4];
  const int bm = blockIdx.y * BM, bn = blockIdx.x * BN;
  const int tid = threadIdx.x;          // 256 threads
  const int tx = tid & 15, ty = tid >> 4;
  const int arow = tid >> 2;            // 0..63
  const int akk  = (tid & 3) << 2;      // 0,4,8,12
  float acc[4][4] = {{0.f}};
  for (int k0 = 0; k0 < K; k0 += BK) {
    float4 av = *(const float4*)&A[(size_t)(bm + arow) * K + k0 + akk];
    As[akk+0][arow] = av.x; As[akk+1][arow] = av.y;
    As[akk+2][arow] = av.z; As[akk+3][arow] = av.w;
    float4 wv = make_float4(0.f, 0.f, 0.f, 0.f);
    if (bn + arow < N) wv = *(const float4*)&W[(size_t)(bn + arow) * K + k0 + akk];
    Ws[akk+0][arow] = wv.x; Ws[akk+1][arow] = wv.y;
    Ws[akk+2][arow] = wv.z; Ws[akk+3][arow] = wv.w;
    __syncthreads();
    #pragma unroll
    for (int kk = 0; kk < BK; kk++) {
      float a[4], b[4];
      #pragma unroll
      for (int i = 0; i < 4; i++) a[i] = As[kk][ty*4 + i];
      #pragma unroll
      for (int j = 0; j < 4; j++) b[j] = Ws[kk][tx*4 + j];
      #pragma unroll
      for (int i = 0; i < 4; i++)
        #pragma unroll
        for (int j = 0; j < 4; j++)
          acc[i][j] = fmaf(a[i], b[j], acc[i][j]);
    }
    __syncthreads();
  }
  #pragma unroll
  for (int i = 0; i < 4; i++) {
    const int m = bm + ty*4 + i;
    #pragma unroll
    for (int j = 0; j < 4; j++) {
      const int n = bn + tx*4 + j;
      if (n < N) C[(size_t)m * N + n] = acc[i][j];
    }
  }
}

// Per (b,t,h): RMSNorm(64)+RoPE; output bf16 [b,h,t,64] with 1/8 scale folded in.
__global__ void prep_q(const float* __restrict__ q, const float* __restrict__ qw,
                       const float* __restrict__ cosp, const float* __restrict__ sinp,
                       __hip_bfloat16* __restrict__ qb)
{
  const int lane = threadIdx.x;          // 0..63
  const int bth = blockIdx.x;            // (b*T + t)*NH + h
  const int h = bth % NH;
  const int bt = bth / NH;
  const int t = bt % T_;
  const int b = bt / T_;
  float v = q[(size_t)bth * 64 + lane];
  const float ss = wred_sum(v * v);
  const float norm = rsqrtf(ss * (1.0f/64.0f) + EPS);
  v = v * norm * qw[lane];
  const float partner = __shfl_xor(v, 8, 64);   // pairs 48..55 <-> 56..63
  if (lane >= 48) {
    const int j = lane & 7;
    const float c = cosp[t*8 + j], s = sinp[t*8 + j];
    v = (lane < 56) ? (v * c - partner * s)
                    : (v * c + partner * s);
  }
  qb[((size_t)(b*NH + h)*T_ + t)*64 + lane] = __float2bfloat16(v * 0.125f);
}

// Per (b,t): RMSNorm over kv_a[:128] -> kvl; RoPE on kv_a[128:144] -> krope.
__global__ void prep_kv(const float* __restrict__ kva, const float* __restrict__ kw,
                        const float* __restrict__ cosp, const float* __restrict__ sinp,
                        float* __restrict__ kvl, float* __restrict__ krope)
{
  const int tid = threadIdx.x;   // 0..127
  const int bt = blockIdx.x;     // 0..B*T-1
  const int t = bt % T_;
  const float* row = kva + (size_t)bt * 144;
  const float v = row[tid];
  float s = wred_sum(v * v);
  __shared__ float red[2];
  if ((tid & 63) == 0) red[tid >> 6] = s;
  __syncthreads();
  const float total = red[0] + red[1];
  const float norm = rsqrtf(total * (1.0f/128.0f) + EPS);
  kvl[(size_t)bt * 128 + tid] = v * norm * kw[tid];
  if (tid < 16) {
    const int j = tid & 7;
    const float c = cosp[t*8 + j], sn = sinp[t*8 + j];
    const float x1 = row[128 + j], x2 = row[136 + j];
    krope[(size_t)bt * 16 + tid] = (tid < 8) ? (x1 * c - x2 * sn)
                                             : (x2 * c + x1 * sn);
  }
}

// Pack per (b,h,64-t tile): kb16[b,h,t,64] = [k_nope(48) | k_rope(16)] bf16;
// vt16[b,h,d,t] = V transposed bf16 (so PV B-frags are 16B-contiguous in t).
__global__ __launch_bounds__(256)
void pack_kv(const float* __restrict__ kvb, const float* __restrict__ krope,
             __hip_bfloat16* __restrict__ kb, __hip_bfloat16* __restrict__ vt)
{
  __shared__ float Vl[64][65];
  const int tid = threadIdx.x;
  const int t0 = blockIdx.x * 64;
  const int bh = blockIdx.y;
  const int b = bh >> 4, h = bh & 15;
  const int r = tid >> 2, c = tid & 3;       // row 0..63, 16-col quarter 0..3
  {
    const size_t row = (size_t)(b*T_ + t0 + r);
    const float* src = (c < 3) ? kvb + row*1792 + h*112 + c*16
                               : krope + row*16;
    __hip_bfloat162* dst = (__hip_bfloat162*)(kb + ((size_t)bh*T_ + t0 + r)*64 + c*16);
    #pragma unroll
    for (int j = 0; j < 8; j++)
      dst[j] = __float22bfloat162_rn(make_float2(src[2*j], src[2*j+1]));
    const float* vsrc = kvb + row*1792 + h*112 + 48 + c*16;
    #pragma unroll
    for (int j = 0; j < 16; j += 4) {
      float4 v4 = *(const float4*)(vsrc + j);
      Vl[r][c*16+j+0] = v4.x; Vl[r][c*16+j+1] = v4.y;
      Vl[r][c*16+j+2] = v4.z; Vl[r][c*16+j+3] = v4.w;
    }
  }
  __syncthreads();
  const int d = tid >> 2, tq = tid & 3;
  __hip_bfloat162* vd = (__hip_bfloat162*)(vt + ((size_t)bh*64 + d)*T_ + t0 + tq*16);
  #pragma unroll
  for (int j = 0; j < 8; j++)
    vd[j] = __float22bfloat162_rn(make_float2(Vl[tq*16 + 2*j][d], Vl[tq*16 + 2*j + 1][d]));
}

// MFMA flash attention. Block = 4 waves = 64 queries of one (b,h); each wave
// owns 16 queries independently (no LDS, no __syncthreads in the loop).
// S^T = K·Q^T via mfma_f32_16x16x32_bf16 (frag: lane&15=row, k=quad*8+j;
// C/D: col=lane&15, row=quad*4+reg). P transposed to A-layout via bpermute.
__global__ __launch_bounds__(256)
void attn_mfma(const __hip_bfloat16* __restrict__ qb,
               const __hip_bfloat16* __restrict__ kbuf,
               const __hip_bfloat16* __restrict__ vbuf,
               float* __restrict__ aout)
{
  const int tid = threadIdx.x;
  const int wv = tid >> 6, lane = tid & 63;
  const int m = lane & 15, quad = lane >> 4;
  const int qt0 = blockIdx.x * 64;
  const int bh = blockIdx.y;
  const int b = bh >> 4, h = bh & 15;
  const int qrow0 = qt0 + wv*16;
  const int qglob = qrow0 + m;           // this lane's query (S^T column)

  const __hip_bfloat16* qrow = qb + ((size_t)bh*T_ + qrow0 + m)*64 + quad*8;
  const bf16x8 qf0 = *(const bf16x8*)(qrow);
  const bf16x8 qf1 = *(const bf16x8*)(qrow + 32);

  const __hip_bfloat16* kp = kbuf + (size_t)bh*T_*64;
  const __hip_bfloat16* vp = vbuf + (size_t)bh*64*T_;

  f32x4 oacc[4];
  #pragma unroll
  for (int vs = 0; vs < 4; vs++) oacc[vs] = (f32x4){0.f,0.f,0.f,0.f};
  float mrun = -3.0e38f, lrun = 0.f;

  const int lastk = qt0 >> 6;
  for (int kt = 0; kt <= lastk; kt++) {
    const int k0 = kt << 6;

    // ---- S^T tile: 64 keys x 16 queries ----
    f32x4 s[4];
    #pragma unroll
    for (int sub = 0; sub < 4; sub++) {
      const __hip_bfloat16* kr = kp + (size_t)(k0 + sub*16 + m)*64 + quad*8;
      const bf16x8 kf0 = *(const bf16x8*)(kr);
      const bf16x8 kf1 = *(const bf16x8*)(kr + 32);
      f32x4 z = (f32x4){0.f,0.f,0.f,0.f};
      z = __builtin_amdgcn_mfma_f32_16x16x32_bf16(kf0, qf0, z, 0, 0, 0);
      z = __builtin_amdgcn_mfma_f32_16x16x32_bf16(kf1, qf1, z, 0, 0, 0);
      s[sub] = z;
    }

    // ---- causal mask on the last tile ----
    if (kt == lastk) {
      #pragma unroll
      for (int sub = 0; sub < 4; sub++)
        #pragma unroll
        for (int r = 0; r < 4; r++)
          if (k0 + sub*16 + quad*4 + r > qglob) s[sub][r] = -1e30f;
    }

    // ---- online softmax (per-query state replicated across the 4 quads) ----
    float tm = -3.0e38f;
    #pragma unroll
    for (int sub = 0; sub < 4; sub++)
      #pragma unroll
      for (int r = 0; r < 4; r++) tm = fmaxf(tm, s[sub][r]);
    tm = fmaxf(tm, __shfl_xor(tm, 16, 64));
    tm = fmaxf(tm, __shfl_xor(tm, 32, 64));
    const float mn = fmaxf(mrun, tm);
    const float alpha = __expf(mrun - mn);
    float rs = 0.f;
    float p[4][4];
    #pragma unroll
    for (int sub = 0; sub < 4; sub++)
      #pragma unroll
      for (int r = 0; r < 4; r++) {
        const float e = __expf(s[sub][r] - mn);
        p[sub][r] = e; rs += e;
      }
    rs += __shfl_xor(rs, 16, 64);
    rs += __shfl_xor(rs, 32, 64);
    lrun = lrun * alpha + rs;
    mrun = mn;

    // ---- transpose P (S^T frag) -> A-operand frags, in-register ----
    unsigned u[4][2];
    #pragma unroll
    for (int sub = 0; sub < 4; sub++) {
      u[sub][0] = pack_bf16(p[sub][0], p[sub][1]);
      u[sub][1] = pack_bf16(p[sub][2], p[sub][3]);
    }
    union { int i[4]; bf16x8 v; } a0u, a1u;
    #pragma unroll
    for (int w4 = 0; w4 < 4; w4++) {
      const int src = (((2*quad + (w4 >> 1)) & 3) << 4) | m;
      const int lo0 = __shfl((int)u[0][w4 & 1], src, 64);
      const int lo1 = __shfl((int)u[1][w4 & 1], src, 64);
      const int hi0 = __shfl((int)u[2][w4 & 1], src, 64);
      const int hi1 = __shfl((int)u[3][w4 & 1], src, 64);
      a0u.i[w4] = (quad & 2) ? lo1 : lo0;
      a1u.i[w4] = (quad & 2) ? hi1 : hi0;
    }

    // ---- rescale O by alpha (alpha indexed by O-frag row = quad*4+reg) ----
    float al[4];
    #pragma unroll
    for (int r = 0; r < 4; r++) al[r] = __shfl(alpha, (quad << 2) | r, 64);
    #pragma unroll
    for (int vs = 0; vs < 4; vs++)
      #pragma unroll
      for (int r = 0; r < 4; r++) oacc[vs][r] *= al[r];

    // ---- O += P V ----
    #pragma unroll
    for (int vs = 0; vs < 4; vs++) {
      const __hip_bfloat16* vr = vp + (size_t)(vs*16 + m)*T_ + k0 + quad*8;
      const bf16x8 vf0 = *(const bf16x8*)(vr);
      const bf16x8 vf1 = *(const bf16x8*)(vr + 32);
      oacc[vs] = __builtin_amdgcn_mfma_f32_16x16x32_bf16(a0u.v, vf0, oacc[vs], 0, 0, 0);
      oacc[vs] = __builtin_amdgcn_mfma_f32_16x16x32_bf16(a1u.v, vf1, oacc[vs], 0, 0, 0);
    }
  }

  // ---- epilogue ----
  float lr[4];
  #pragma unroll
  for (int r = 0; r < 4; r++) lr[r] = __shfl(lrun, (quad << 2) | r, 64);
  #pragma unroll
  for (int vs = 0; vs < 4; vs++)
    #pragma unroll
    for (int r = 0; r < 4; r++)
      aout[(size_t)(b*T_ + qrow0 + quad*4 + r) * 1024 + h*64 + vs*16 + m]
          = oacc[vs][r] / lr[r];
}

extern "C" void kernel_launch(void* const* d_in, const int* in_sizes, int n_in,
                              void* d_out, int out_size, void* d_ws, size_t ws_size,
                              hipStream_t stream)
{
  const float* x    = (const float*)d_in[0];
  const float* cosp = (const float*)d_in[1];
  const float* sinp = (const float*)d_in[2];
  const float* Wq   = (const float*)d_in[3];
  const float* qw   = (const float*)d_in[4];
  const float* Wkva = (const float*)d_in[5];
  const float* kw   = (const float*)d_in[6];
  const float* Wkvb = (const float*)d_in[7];
  const float* Wo   = (const float*)d_in[8];
  float* out = (float*)d_out;

  float* ws    = (float*)d_ws;
  float* q     = ws;                    // B*T*NH*64      = 4,194,304 f
  float* kva   = q     + 4194304;       // B*T*144        =   589,824 f
  float* kvl   = kva   + 589824;        // B*T*128        =   524,288 f
  float* krope = kvl   + 524288;        // B*T*16         =    65,536 f
  float* kvb   = krope + 65536;         // B*T*1792       = 7,340,032 f
  float* aout  = kvb   + 7340032;       // B*T*1024       = 4,194,304 f
  __hip_bfloat16* qb16 = (__hip_bfloat16*)(aout + 4194304);  // B*NH*T*64 bf16
  __hip_bfloat16* kb16 = qb16 + 4194304;                      // B*NH*T*64 bf16
  __hip_bfloat16* vt16 = kb16 + 4194304;                      // B*NH*64*T bf16

  const int M = B_ * T_;                // 4096

  gemm_nt<64,64,16><<<dim3(1024/64, M/64), 256, 0, stream>>>(x, Wq, q, M, 1024, 1024);
  gemm_nt<64,64,16><<<dim3(3, M/64), 256, 0, stream>>>(x, Wkva, kva, M, 144, 1024);
  prep_q<<<M * NH, 64, 0, stream>>>(q, qw, cosp, sinp, qb16);
  prep_kv<<<M, 128, 0, stream>>>(kva, kw, cosp, sinp, kvl, krope);
  gemm_nt<64,64,16><<<dim3(1792/64, M/64), 256, 0, stream>>>(kvl, Wkvb, kvb, M, 1792, 128);
  pack_kv<<<dim3(T_/64, B_ * NH), 256, 0, stream>>>(kvb, krope, kb16, vt16);
  attn_mfma<<<dim3(T_/64, B_ * NH), 256, 0, stream>>>(qb16, kb16, vt16, aout);
  gemm_nt<64,64,16><<<dim3(1024/64, M/64), 256, 0, stream>>>(aout, Wo, out, M, 1024, 1024);
}

// Round 4
// 414.319 us; speedup vs baseline: 23.5019x; 1.6354x over previous
//
#include <hip/hip_runtime.h>
#include <hip/hip_bf16.h>
#include <math.h>

#define NH 16
#define T_ 2048
#define B_ 2
#define D_ 1024
#define EPS 1e-6f

typedef __attribute__((ext_vector_type(8))) short bf16x8;
typedef __attribute__((ext_vector_type(4))) float f32x4;

__device__ __forceinline__ float wred_sum(float v){
  #pragma unroll
  for (int o = 32; o > 0; o >>= 1) v += __shfl_xor(v, o, 64);
  return v;
}

__device__ __forceinline__ unsigned pack_bf16(float a, float b){
  __hip_bfloat162 t = __float22bfloat162_rn(make_float2(a, b));
  unsigned r; __builtin_memcpy(&r, &t, 4); return r;
}

__device__ __forceinline__ void gload_lds16(const void* g, void* l){
  __builtin_amdgcn_global_load_lds((const __attribute__((address_space(1))) void*)g,
                                   (__attribute__((address_space(3))) void*)l, 16, 0, 0);
}

// ---- convert x + all weights to bf16 in one pass (float4-indexed segments) ----
__global__ __launch_bounds__(256)
void cvt5(const float* __restrict__ x, const float* __restrict__ wq,
          const float* __restrict__ wkva, const float* __restrict__ wkvb,
          const float* __restrict__ wo,
          __hip_bfloat16* __restrict__ xb, __hip_bfloat16* __restrict__ wqb,
          __hip_bfloat16* __restrict__ wkvab, __hip_bfloat16* __restrict__ wkvbb,
          __hip_bfloat16* __restrict__ wob)
{
  const int i = blockIdx.x * 256 + threadIdx.x;     // float4 index, 1,667,072 total
  const float* s; __hip_bfloat16* d; int off;
  if      (i < 1048576) { s = x;    d = xb;    off = i; }
  else if (i < 1310720) { s = wq;   d = wqb;   off = i - 1048576; }
  else if (i < 1347584) { s = wkva; d = wkvab; off = i - 1310720; }
  else if (i < 1404928) { s = wkvb; d = wkvbb; off = i - 1347584; }
  else                  { s = wo;   d = wob;   off = i - 1404928; }
  float4 v = *(const float4*)(s + (size_t)off * 4);
  *(__hip_bfloat162*)(d + (size_t)off * 4)     = __float22bfloat162_rn(make_float2(v.x, v.y));
  *(__hip_bfloat162*)(d + (size_t)off * 4 + 2) = __float22bfloat162_rn(make_float2(v.z, v.w));
}

// ---- bf16 MFMA GEMM: C(f32 MxN) = A(MxK bf16) · W^T (W: NxK bf16) ----
// m97 structure: 128x128 tile, BK=64, global_load_lds width=16, XOR-swizzled LDS
// columns (staging stays lane-contiguous; frag ds_read_b128 <=2-way per quad).
// M % 128 == 0, K % 64 == 0 required; N handled by clamp+predication.
__global__ __launch_bounds__(256)
void gemm_bt(const __hip_bfloat16* __restrict__ A, const __hip_bfloat16* __restrict__ W,
             float* __restrict__ C, int M, int N, int K)
{
  __shared__ __hip_bfloat16 As[128 * 64];   // 16 KB
  __shared__ __hip_bfloat16 Ws[128 * 64];   // 16 KB
  const int tid = threadIdx.x;
  const int wv = tid >> 6, lane = tid & 63;
  const int m = lane & 15, quad = lane >> 4;
  const int bm = blockIdx.y * 128, bn = blockIdx.x * 128;
  const int wm = wv >> 1, wn = wv & 1;

  // staging: wave wv covers rows wv*32 + i*8 + (lane>>3); 8B cols XOR-swizzled
  const int srow = lane >> 3;                       // 0..7
  const int scol = ((lane & 7) ^ srow) << 3;        // swizzled elem col
  const __hip_bfloat16* ga[4];
  const __hip_bfloat16* gw[4];
  #pragma unroll
  for (int i = 0; i < 4; i++) {
    ga[i] = A + (size_t)(bm + wv*32 + i*8 + srow) * K + scol;
    int wr = bn + wv*32 + i*8 + srow; if (wr >= N) wr = N - 1;
    gw[i] = W + (size_t)wr * K + scol;
  }

  f32x4 acc[4][4];
  #pragma unroll
  for (int mi = 0; mi < 4; mi++)
    #pragma unroll
    for (int nj = 0; nj < 4; nj++) acc[mi][nj] = (f32x4){0.f,0.f,0.f,0.f};

  for (int k0 = 0; k0 < K; k0 += 64) {
    #pragma unroll
    for (int i = 0; i < 4; i++) {
      gload_lds16(ga[i], As + (wv*32 + i*8) * 64);
      gload_lds16(gw[i], Ws + (wv*32 + i*8) * 64);
      ga[i] += 64; gw[i] += 64;
    }
    __syncthreads();
    #pragma unroll
    for (int ks = 0; ks < 2; ks++) {
      const int cb = ((quad + ks*4) ^ (m & 7)) << 3;   // swizzled col offset
      bf16x8 af[4], wf[4];
      #pragma unroll
      for (int mi = 0; mi < 4; mi++)
        af[mi] = *(const bf16x8*)(As + (wm*64 + mi*16 + m) * 64 + cb);
      #pragma unroll
      for (int nj = 0; nj < 4; nj++)
        wf[nj] = *(const bf16x8*)(Ws + (wn*64 + nj*16 + m) * 64 + cb);
      #pragma unroll
      for (int mi = 0; mi < 4; mi++)
        #pragma unroll
        for (int nj = 0; nj < 4; nj++)
          acc[mi][nj] = __builtin_amdgcn_mfma_f32_16x16x32_bf16(af[mi], wf[nj], acc[mi][nj], 0, 0, 0);
    }
    __syncthreads();
  }

  #pragma unroll
  for (int mi = 0; mi < 4; mi++)
    #pragma unroll
    for (int nj = 0; nj < 4; nj++) {
      const int col = bn + wn*64 + nj*16 + m;
      if (col < N) {
        #pragma unroll
        for (int r = 0; r < 4; r++) {
          const int row = bm + wm*64 + mi*16 + quad*4 + r;
          C[(size_t)row * N + col] = acc[mi][nj][r];
        }
      }
    }
}

// Per (b,t,h): RMSNorm(64)+RoPE; output bf16 [b,h,t,64] with 1/8 scale folded in.
__global__ void prep_q(const float* __restrict__ q, const float* __restrict__ qw,
                       const float* __restrict__ cosp, const float* __restrict__ sinp,
                       __hip_bfloat16* __restrict__ qb)
{
  const int lane = threadIdx.x;          // 0..63
  const int bth = blockIdx.x;            // (b*T + t)*NH + h
  const int h = bth % NH;
  const int bt = bth / NH;
  const int t = bt % T_;
  const int b = bt / T_;
  float v = q[(size_t)bth * 64 + lane];
  const float ss = wred_sum(v * v);
  const float norm = rsqrtf(ss * (1.0f/64.0f) + EPS);
  v = v * norm * qw[lane];
  const float partner = __shfl_xor(v, 8, 64);
  if (lane >= 48) {
    const int j = lane & 7;
    const float c = cosp[t*8 + j], s = sinp[t*8 + j];
    v = (lane < 56) ? (v * c - partner * s)
                    : (v * c + partner * s);
  }
  qb[((size_t)(b*NH + h)*T_ + t)*64 + lane] = __float2bfloat16(v * 0.125f);
}

// Per (b,t): RMSNorm over kv_a[:128] -> kvl16 (bf16); RoPE on kv_a[128:144] -> krope.
__global__ void prep_kv(const float* __restrict__ kva, const float* __restrict__ kw,
                        const float* __restrict__ cosp, const float* __restrict__ sinp,
                        __hip_bfloat16* __restrict__ kvl16, float* __restrict__ krope)
{
  const int tid = threadIdx.x;   // 0..127
  const int bt = blockIdx.x;
  const int t = bt % T_;
  const float* row = kva + (size_t)bt * 144;
  const float v = row[tid];
  float s = wred_sum(v * v);
  __shared__ float red[2];
  if ((tid & 63) == 0) red[tid >> 6] = s;
  __syncthreads();
  const float total = red[0] + red[1];
  const float norm = rsqrtf(total * (1.0f/128.0f) + EPS);
  kvl16[(size_t)bt * 128 + tid] = __float2bfloat16(v * norm * kw[tid]);
  if (tid < 16) {
    const int j = tid & 7;
    const float c = cosp[t*8 + j], sn = sinp[t*8 + j];
    const float x1 = row[128 + j], x2 = row[136 + j];
    krope[(size_t)bt * 16 + tid] = (tid < 8) ? (x1 * c - x2 * sn)
                                             : (x2 * c + x1 * sn);
  }
}

// Pack per (b,h,64-t tile): kb16[b,h,t,64] = [k_nope(48) | k_rope(16)];
// vt16[b,h,d,t] = V transposed.
__global__ __launch_bounds__(256)
void pack_kv(const float* __restrict__ kvb, const float* __restrict__ krope,
             __hip_bfloat16* __restrict__ kb, __hip_bfloat16* __restrict__ vt)
{
  __shared__ float Vl[64][65];
  const int tid = threadIdx.x;
  const int t0 = blockIdx.x * 64;
  const int bh = blockIdx.y;
  const int b = bh >> 4, h = bh & 15;
  const int r = tid >> 2, c = tid & 3;
  {
    const size_t row = (size_t)(b*T_ + t0 + r);
    const float* src = (c < 3) ? kvb + row*1792 + h*112 + c*16
                               : krope + row*16;
    __hip_bfloat162* dst = (__hip_bfloat162*)(kb + ((size_t)bh*T_ + t0 + r)*64 + c*16);
    #pragma unroll
    for (int j = 0; j < 8; j++)
      dst[j] = __float22bfloat162_rn(make_float2(src[2*j], src[2*j+1]));
    const float* vsrc = kvb + row*1792 + h*112 + 48 + c*16;
    #pragma unroll
    for (int j = 0; j < 16; j += 4) {
      float4 v4 = *(const float4*)(vsrc + j);
      Vl[r][c*16+j+0] = v4.x; Vl[r][c*16+j+1] = v4.y;
      Vl[r][c*16+j+2] = v4.z; Vl[r][c*16+j+3] = v4.w;
    }
  }
  __syncthreads();
  const int d = tid >> 2, tq = tid & 3;
  __hip_bfloat162* vd = (__hip_bfloat162*)(vt + ((size_t)bh*64 + d)*T_ + t0 + tq*16);
  #pragma unroll
  for (int j = 0; j < 8; j++)
    vd[j] = __float22bfloat162_rn(make_float2(Vl[tq*16 + 2*j][d], Vl[tq*16 + 2*j + 1][d]));
}

// MFMA flash attention with K-prefetch and early V loads. Block = 4 waves =
// 64 queries of one (b,h); no LDS, no barriers. qtile reversed: longest first.
__global__ __launch_bounds__(256)
void attn_mfma(const __hip_bfloat16* __restrict__ qb,
               const __hip_bfloat16* __restrict__ kbuf,
               const __hip_bfloat16* __restrict__ vbuf,
               __hip_bfloat16* __restrict__ aout)
{
  const int tid = threadIdx.x;
  const int wv = tid >> 6, lane = tid & 63;
  const int m = lane & 15, quad = lane >> 4;
  const int qt0 = (31 - blockIdx.x) * 64;     // longest blocks dispatched first
  const int bh = blockIdx.y;
  const int b = bh >> 4, h = bh & 15;
  const int qrow0 = qt0 + wv*16;
  const int qglob = qrow0 + m;

  const __hip_bfloat16* qrow = qb + ((size_t)bh*T_ + qrow0 + m)*64 + quad*8;
  const bf16x8 qf0 = *(const bf16x8*)(qrow);
  const bf16x8 qf1 = *(const bf16x8*)(qrow + 32);

  const __hip_bfloat16* kp = kbuf + (size_t)bh*T_*64;
  const __hip_bfloat16* vp = vbuf + (size_t)bh*64*T_;

  f32x4 oacc[4];
  #pragma unroll
  for (int vs = 0; vs < 4; vs++) oacc[vs] = (f32x4){0.f,0.f,0.f,0.f};
  float mrun = -3.0e38f, lrun = 0.f;

  const int lastk = qt0 >> 6;

  // preload K tile 0 fragments
  bf16x8 kf0[4], kf1[4];
  #pragma unroll
  for (int sub = 0; sub < 4; sub++) {
    const __hip_bfloat16* kr = kp + (size_t)(sub*16 + m)*64 + quad*8;
    kf0[sub] = *(const bf16x8*)(kr);
    kf1[sub] = *(const bf16x8*)(kr + 32);
  }

  for (int kt = 0; kt <= lastk; kt++) {
    const int k0 = kt << 6;

    // ---- V loads for this tile, issued early (used after softmax) ----
    bf16x8 vf0[4], vf1[4];
    #pragma unroll
    for (int vs = 0; vs < 4; vs++) {
      const __hip_bfloat16* vr = vp + (size_t)(vs*16 + m)*T_ + k0 + quad*8;
      vf0[vs] = *(const bf16x8*)(vr);
      vf1[vs] = *(const bf16x8*)(vr + 32);
    }

    // ---- S^T tile from preloaded K frags ----
    f32x4 s[4];
    #pragma unroll
    for (int sub = 0; sub < 4; sub++) {
      f32x4 z = (f32x4){0.f,0.f,0.f,0.f};
      z = __builtin_amdgcn_mfma_f32_16x16x32_bf16(kf0[sub], qf0, z, 0, 0, 0);
      z = __builtin_amdgcn_mfma_f32_16x16x32_bf16(kf1[sub], qf1, z, 0, 0, 0);
      s[sub] = z;
    }

    // ---- prefetch next K tile (clamped: redundant on last iter, branchless) ----
    const int kn = (kt < lastk) ? (k0 + 64) : k0;
    bf16x8 nk0[4], nk1[4];
    #pragma unroll
    for (int sub = 0; sub < 4; sub++) {
      const __hip_bfloat16* kr = kp + (size_t)(kn + sub*16 + m)*64 + quad*8;
      nk0[sub] = *(const bf16x8*)(kr);
      nk1[sub] = *(const bf16x8*)(kr + 32);
    }

    // ---- causal mask on the last tile ----
    if (kt == lastk) {
      #pragma unroll
      for (int sub = 0; sub < 4; sub++)
        #pragma unroll
        for (int r = 0; r < 4; r++)
          if (k0 + sub*16 + quad*4 + r > qglob) s[sub][r] = -1e30f;
    }

    // ---- online softmax ----
    float tm = -3.0e38f;
    #pragma unroll
    for (int sub = 0; sub < 4; sub++)
      #pragma unroll
      for (int r = 0; r < 4; r++) tm = fmaxf(tm, s[sub][r]);
    tm = fmaxf(tm, __shfl_xor(tm, 16, 64));
    tm = fmaxf(tm, __shfl_xor(tm, 32, 64));
    const float mn = fmaxf(mrun, tm);
    const float alpha = __expf(mrun - mn);
    float rs = 0.f;
    float p[4][4];
    #pragma unroll
    for (int sub = 0; sub < 4; sub++)
      #pragma unroll
      for (int r = 0; r < 4; r++) {
        const float e = __expf(s[sub][r] - mn);
        p[sub][r] = e; rs += e;
      }
    rs += __shfl_xor(rs, 16, 64);
    rs += __shfl_xor(rs, 32, 64);
    lrun = lrun * alpha + rs;
    mrun = mn;

    // ---- transpose P -> A-operand frags, in-register ----
    unsigned u[4][2];
    #pragma unroll
    for (int sub = 0; sub < 4; sub++) {
      u[sub][0] = pack_bf16(p[sub][0], p[sub][1]);
      u[sub][1] = pack_bf16(p[sub][2], p[sub][3]);
    }
    union { int i[4]; bf16x8 v; } a0u, a1u;
    #pragma unroll
    for (int w4 = 0; w4 < 4; w4++) {
      const int src = (((2*quad + (w4 >> 1)) & 3) << 4) | m;
      const int lo0 = __shfl((int)u[0][w4 & 1], src, 64);
      const int lo1 = __shfl((int)u[1][w4 & 1], src, 64);
      const int hi0 = __shfl((int)u[2][w4 & 1], src, 64);
      const int hi1 = __shfl((int)u[3][w4 & 1], src, 64);
      a0u.i[w4] = (quad & 2) ? lo1 : lo0;
      a1u.i[w4] = (quad & 2) ? hi1 : hi0;
    }

    // ---- rescale O ----
    float al[4];
    #pragma unroll
    for (int r = 0; r < 4; r++) al[r] = __shfl(alpha, (quad << 2) | r, 64);
    #pragma unroll
    for (int vs = 0; vs < 4; vs++)
      #pragma unroll
      for (int r = 0; r < 4; r++) oacc[vs][r] *= al[r];

    // ---- O += P V ----
    #pragma unroll
    for (int vs = 0; vs < 4; vs++) {
      oacc[vs] = __builtin_amdgcn_mfma_f32_16x16x32_bf16(a0u.v, vf0[vs], oacc[vs], 0, 0, 0);
      oacc[vs] = __builtin_amdgcn_mfma_f32_16x16x32_bf16(a1u.v, vf1[vs], oacc[vs], 0, 0, 0);
    }

    // ---- rotate prefetched K ----
    #pragma unroll
    for (int sub = 0; sub < 4; sub++) { kf0[sub] = nk0[sub]; kf1[sub] = nk1[sub]; }
  }

  // ---- epilogue: normalize, store bf16 (A-operand of the Wo GEMM) ----
  float lr[4];
  #pragma unroll
  for (int r = 0; r < 4; r++) lr[r] = __shfl(lrun, (quad << 2) | r, 64);
  #pragma unroll
  for (int vs = 0; vs < 4; vs++)
    #pragma unroll
    for (int r = 0; r < 4; r++)
      aout[(size_t)(b*T_ + qrow0 + quad*4 + r) * 1024 + h*64 + vs*16 + m]
          = __float2bfloat16(oacc[vs][r] / lr[r]);
}

extern "C" void kernel_launch(void* const* d_in, const int* in_sizes, int n_in,
                              void* d_out, int out_size, void* d_ws, size_t ws_size,
                              hipStream_t stream)
{
  const float* x    = (const float*)d_in[0];
  const float* cosp = (const float*)d_in[1];
  const float* sinp = (const float*)d_in[2];
  const float* Wq   = (const float*)d_in[3];
  const float* qw   = (const float*)d_in[4];
  const float* Wkva = (const float*)d_in[5];
  const float* kw   = (const float*)d_in[6];
  const float* Wkvb = (const float*)d_in[7];
  const float* Wo   = (const float*)d_in[8];
  float* out = (float*)d_out;

  float* q     = (float*)d_ws;          // 4,194,304 f   (dead after prep_q -> ab16 alias)
  float* kva   = q + 4194304;           //   589,824 f
  float* krope = kva + 589824;          //    65,536 f
  float* kvb   = krope + 65536;         // 7,340,032 f   (written step 6; xb16 alias until then)
  __hip_bfloat16* kvl16 = (__hip_bfloat16*)(kvb + 7340032);   //   524,288
  __hip_bfloat16* qb16  = kvl16 + 524288;                      // 4,194,304
  __hip_bfloat16* kb16  = qb16 + 4194304;                      // 4,194,304
  __hip_bfloat16* vt16  = kb16 + 4194304;                      // 4,194,304
  __hip_bfloat16* Wqb   = vt16 + 4194304;                      // 1,048,576
  __hip_bfloat16* Wkvab = Wqb + 1048576;                       //   147,456
  __hip_bfloat16* Wkvbb = Wkvab + 147456;                      //   229,376
  __hip_bfloat16* Wob   = Wkvbb + 229376;                      // 1,048,576
  __hip_bfloat16* xb16  = (__hip_bfloat16*)kvb;   // alias: dead before kvb written
  __hip_bfloat16* ab16  = (__hip_bfloat16*)q;     // alias: q dead before attn writes

  const int M = B_ * T_;   // 4096

  cvt5<<<6512, 256, 0, stream>>>(x, Wq, Wkva, Wkvb, Wo, xb16, Wqb, Wkvab, Wkvbb, Wob);
  gemm_bt<<<dim3(8, 32), 256, 0, stream>>>(xb16, Wqb, q, M, 1024, 1024);
  gemm_bt<<<dim3(2, 32), 256, 0, stream>>>(xb16, Wkvab, kva, M, 144, 1024);
  prep_q<<<M * NH, 64, 0, stream>>>(q, qw, cosp, sinp, qb16);
  prep_kv<<<M, 128, 0, stream>>>(kva, kw, cosp, sinp, kvl16, krope);
  gemm_bt<<<dim3(14, 32), 256, 0, stream>>>(kvl16, Wkvbb, kvb, M, 1792, 128);
  pack_kv<<<dim3(T_/64, B_ * NH), 256, 0, stream>>>(kvb, krope, kb16, vt16);
  attn_mfma<<<dim3(T_/64, B_ * NH), 256, 0, stream>>>(qb16, kb16, vt16, ab16);
  gemm_bt<<<dim3(8, 32), 256, 0, stream>>>(ab16, Wob, out, M, 1024, 1024);
}

// Round 5
// 250.700 us; speedup vs baseline: 38.8404x; 1.6526x over previous
//
#include <hip/hip_runtime.h>
#include <hip/hip_bf16.h>
#include <math.h>

#define NH 16
#define T_ 2048
#define B_ 2
#define D_ 1024
#define EPS 1e-6f

typedef __attribute__((ext_vector_type(8))) short bf16x8;
typedef __attribute__((ext_vector_type(4))) float f32x4;

__device__ __forceinline__ float wred_sum(float v){
  #pragma unroll
  for (int o = 32; o > 0; o >>= 1) v += __shfl_xor(v, o, 64);
  return v;
}

__device__ __forceinline__ unsigned pack_bf16(float a, float b){
  __hip_bfloat162 t = __float22bfloat162_rn(make_float2(a, b));
  unsigned r; __builtin_memcpy(&r, &t, 4); return r;
}

__device__ __forceinline__ void gload_lds16(const void* g, void* l){
  __builtin_amdgcn_global_load_lds((const __attribute__((address_space(1))) void*)g,
                                   (__attribute__((address_space(3))) void*)l, 16, 0, 0);
}

// ---- convert x + all weights to bf16 in one pass (float4-indexed segments) ----
__global__ __launch_bounds__(256)
void cvt5(const float* __restrict__ x, const float* __restrict__ wq,
          const float* __restrict__ wkva, const float* __restrict__ wkvb,
          const float* __restrict__ wo,
          __hip_bfloat16* __restrict__ xb, __hip_bfloat16* __restrict__ wqb,
          __hip_bfloat16* __restrict__ wkvab, __hip_bfloat16* __restrict__ wkvbb,
          __hip_bfloat16* __restrict__ wob)
{
  const int i = blockIdx.x * 256 + threadIdx.x;     // float4 index, 1,667,072 total
  const float* s; __hip_bfloat16* d; int off;
  if      (i < 1048576) { s = x;    d = xb;    off = i; }
  else if (i < 1310720) { s = wq;   d = wqb;   off = i - 1048576; }
  else if (i < 1347584) { s = wkva; d = wkvab; off = i - 1310720; }
  else if (i < 1404928) { s = wkvb; d = wkvbb; off = i - 1347584; }
  else                  { s = wo;   d = wob;   off = i - 1404928; }
  float4 v = *(const float4*)(s + (size_t)off * 4);
  *(__hip_bfloat162*)(d + (size_t)off * 4)     = __float22bfloat162_rn(make_float2(v.x, v.y));
  *(__hip_bfloat162*)(d + (size_t)off * 4 + 2) = __float22bfloat162_rn(make_float2(v.z, v.w));
}

// ---- bf16 MFMA GEMM: C (MxN, f32 or bf16) = A(MxK bf16) · W^T (W: NxK bf16) ----
template<typename CT>
__global__ __launch_bounds__(256)
void gemm_bt(const __hip_bfloat16* __restrict__ A, const __hip_bfloat16* __restrict__ W,
             CT* __restrict__ C, int M, int N, int K)
{
  __shared__ __hip_bfloat16 As[128 * 64];   // 16 KB
  __shared__ __hip_bfloat16 Ws[128 * 64];   // 16 KB
  const int tid = threadIdx.x;
  const int wv = tid >> 6, lane = tid & 63;
  const int m = lane & 15, quad = lane >> 4;
  const int bm = blockIdx.y * 128, bn = blockIdx.x * 128;
  const int wm = wv >> 1, wn = wv & 1;

  const int srow = lane >> 3;                       // 0..7
  const int scol = ((lane & 7) ^ srow) << 3;        // swizzled elem col
  const __hip_bfloat16* ga[4];
  const __hip_bfloat16* gw[4];
  #pragma unroll
  for (int i = 0; i < 4; i++) {
    ga[i] = A + (size_t)(bm + wv*32 + i*8 + srow) * K + scol;
    int wr = bn + wv*32 + i*8 + srow; if (wr >= N) wr = N - 1;
    gw[i] = W + (size_t)wr * K + scol;
  }

  f32x4 acc[4][4];
  #pragma unroll
  for (int mi = 0; mi < 4; mi++)
    #pragma unroll
    for (int nj = 0; nj < 4; nj++) acc[mi][nj] = (f32x4){0.f,0.f,0.f,0.f};

  for (int k0 = 0; k0 < K; k0 += 64) {
    #pragma unroll
    for (int i = 0; i < 4; i++) {
      gload_lds16(ga[i], As + (wv*32 + i*8) * 64);
      gload_lds16(gw[i], Ws + (wv*32 + i*8) * 64);
      ga[i] += 64; gw[i] += 64;
    }
    __syncthreads();
    #pragma unroll
    for (int ks = 0; ks < 2; ks++) {
      const int cb = ((quad + ks*4) ^ (m & 7)) << 3;
      bf16x8 af[4], wf[4];
      #pragma unroll
      for (int mi = 0; mi < 4; mi++)
        af[mi] = *(const bf16x8*)(As + (wm*64 + mi*16 + m) * 64 + cb);
      #pragma unroll
      for (int nj = 0; nj < 4; nj++)
        wf[nj] = *(const bf16x8*)(Ws + (wn*64 + nj*16 + m) * 64 + cb);
      #pragma unroll
      for (int mi = 0; mi < 4; mi++)
        #pragma unroll
        for (int nj = 0; nj < 4; nj++)
          acc[mi][nj] = __builtin_amdgcn_mfma_f32_16x16x32_bf16(af[mi], wf[nj], acc[mi][nj], 0, 0, 0);
    }
    __syncthreads();
  }

  #pragma unroll
  for (int mi = 0; mi < 4; mi++)
    #pragma unroll
    for (int nj = 0; nj < 4; nj++) {
      const int col = bn + wn*64 + nj*16 + m;
      if (col < N) {
        #pragma unroll
        for (int r = 0; r < 4; r++) {
          const int row = bm + wm*64 + mi*16 + quad*4 + r;
          if constexpr (sizeof(CT) == 2)
            C[(size_t)row * N + col] = (CT)__float2bfloat16(acc[mi][nj][r]);
          else
            C[(size_t)row * N + col] = acc[mi][nj][r];
        }
      }
    }
}

// Per (b,t,h): RMSNorm(64)+RoPE; output bf16 [b,h,t,64] with 1/8 scale folded in.
__global__ void prep_q(const float* __restrict__ q, const float* __restrict__ qw,
                       const float* __restrict__ cosp, const float* __restrict__ sinp,
                       __hip_bfloat16* __restrict__ qb)
{
  const int lane = threadIdx.x;          // 0..63
  const int bth = blockIdx.x;            // (b*T + t)*NH + h
  const int h = bth % NH;
  const int bt = bth / NH;
  const int t = bt % T_;
  const int b = bt / T_;
  float v = q[(size_t)bth * 64 + lane];
  const float ss = wred_sum(v * v);
  const float norm = rsqrtf(ss * (1.0f/64.0f) + EPS);
  v = v * norm * qw[lane];
  const float partner = __shfl_xor(v, 8, 64);
  if (lane >= 48) {
    const int j = lane & 7;
    const float c = cosp[t*8 + j], s = sinp[t*8 + j];
    v = (lane < 56) ? (v * c - partner * s)
                    : (v * c + partner * s);
  }
  qb[((size_t)(b*NH + h)*T_ + t)*64 + lane] = __float2bfloat16(v * 0.125f);
}

// Per (b,t): RMSNorm over kv_a[:128] -> kvl16 (bf16); RoPE on kv_a[128:144] -> krope16 (bf16).
__global__ void prep_kv(const float* __restrict__ kva, const float* __restrict__ kw,
                        const float* __restrict__ cosp, const float* __restrict__ sinp,
                        __hip_bfloat16* __restrict__ kvl16, __hip_bfloat16* __restrict__ krope16)
{
  const int tid = threadIdx.x;   // 0..127
  const int bt = blockIdx.x;
  const int t = bt % T_;
  const float* row = kva + (size_t)bt * 144;
  const float v = row[tid];
  float s = wred_sum(v * v);
  __shared__ float red[2];
  if ((tid & 63) == 0) red[tid >> 6] = s;
  __syncthreads();
  const float total = red[0] + red[1];
  const float norm = rsqrtf(total * (1.0f/128.0f) + EPS);
  kvl16[(size_t)bt * 128 + tid] = __float2bfloat16(v * norm * kw[tid]);
  if (tid < 16) {
    const int j = tid & 7;
    const float c = cosp[t*8 + j], sn = sinp[t*8 + j];
    const float x1 = row[128 + j], x2 = row[136 + j];
    krope16[(size_t)bt * 16 + tid] = __float2bfloat16((tid < 8) ? (x1 * c - x2 * sn)
                                                               : (x2 * c + x1 * sn));
  }
}

// vt16[b,h,d,t] = V transposed (V = kvb16 cols 48..111 of head h).
__global__ __launch_bounds__(256)
void pack_v(const __hip_bfloat16* __restrict__ kvb16, __hip_bfloat16* __restrict__ vt)
{
  __shared__ short Vl[64][72];
  const int tid = threadIdx.x;
  const int t0 = blockIdx.x * 64;
  const int bh = blockIdx.y;
  const int b = bh >> 4, h = bh & 15;
  const int r = tid >> 2, c = tid & 3;
  {
    const short* src = (const short*)(kvb16 + ((size_t)(b*T_ + t0 + r)*1792 + h*112 + 48 + c*16));
    union { bf16x8 v; short e[8]; } u0, u1;
    u0.v = *(const bf16x8*)src;
    u1.v = *(const bf16x8*)(src + 8);
    #pragma unroll
    for (int j = 0; j < 8; j++) { Vl[r][c*16+j] = u0.e[j]; Vl[r][c*16+8+j] = u1.e[j]; }
  }
  __syncthreads();
  const int d = tid >> 2, tq = tid & 3;
  union { bf16x8 v; short e[8]; } o0, o1;
  #pragma unroll
  for (int j = 0; j < 8; j++) { o0.e[j] = Vl[tq*16+j][d]; o1.e[j] = Vl[tq*16+8+j][d]; }
  short* dst = (short*)(vt + ((size_t)bh*64 + d)*T_ + t0 + tq*16);
  *(bf16x8*)dst = o0.v;
  *(bf16x8*)(dst + 8) = o1.v;
}

// ---- flash-attention tile update for one softmax state (verbatim-verified math) ----
__device__ __forceinline__ void fa_update(f32x4 (&s)[4], const bool diag,
    const int k0, const int qglob, const int m, const int quad,
    float& mrun, float& lrun, f32x4 (&oacc)[4],
    const bf16x8 (&vf0)[4], const bf16x8 (&vf1)[4])
{
  if (diag) {
    #pragma unroll
    for (int sub = 0; sub < 4; sub++)
      #pragma unroll
      for (int r = 0; r < 4; r++)
        if (k0 + sub*16 + quad*4 + r > qglob) s[sub][r] = -1e30f;
  }
  float tm = -3.0e38f;
  #pragma unroll
  for (int sub = 0; sub < 4; sub++)
    #pragma unroll
    for (int r = 0; r < 4; r++) tm = fmaxf(tm, s[sub][r]);
  tm = fmaxf(tm, __shfl_xor(tm, 16, 64));
  tm = fmaxf(tm, __shfl_xor(tm, 32, 64));
  const float mn = fmaxf(mrun, tm);
  const float alpha = __expf(mrun - mn);
  float rs = 0.f;
  float p[4][4];
  #pragma unroll
  for (int sub = 0; sub < 4; sub++)
    #pragma unroll
    for (int r = 0; r < 4; r++) {
      const float e = __expf(s[sub][r] - mn);
      p[sub][r] = e; rs += e;
    }
  rs += __shfl_xor(rs, 16, 64);
  rs += __shfl_xor(rs, 32, 64);
  lrun = lrun * alpha + rs;
  mrun = mn;

  unsigned u[4][2];
  #pragma unroll
  for (int sub = 0; sub < 4; sub++) {
    u[sub][0] = pack_bf16(p[sub][0], p[sub][1]);
    u[sub][1] = pack_bf16(p[sub][2], p[sub][3]);
  }
  union { int i[4]; bf16x8 v; } a0u, a1u;
  #pragma unroll
  for (int w4 = 0; w4 < 4; w4++) {
    const int src = (((2*quad + (w4 >> 1)) & 3) << 4) | m;
    const int lo0 = __shfl((int)u[0][w4 & 1], src, 64);
    const int lo1 = __shfl((int)u[1][w4 & 1], src, 64);
    const int hi0 = __shfl((int)u[2][w4 & 1], src, 64);
    const int hi1 = __shfl((int)u[3][w4 & 1], src, 64);
    a0u.i[w4] = (quad & 2) ? lo1 : lo0;
    a1u.i[w4] = (quad & 2) ? hi1 : hi0;
  }

  float al[4];
  #pragma unroll
  for (int r = 0; r < 4; r++) al[r] = __shfl(alpha, (quad << 2) | r, 64);
  #pragma unroll
  for (int vs = 0; vs < 4; vs++)
    #pragma unroll
    for (int r = 0; r < 4; r++) oacc[vs][r] *= al[r];

  #pragma unroll
  for (int vs = 0; vs < 4; vs++) {
    oacc[vs] = __builtin_amdgcn_mfma_f32_16x16x32_bf16(a0u.v, vf0[vs], oacc[vs], 0, 0, 0);
    oacc[vs] = __builtin_amdgcn_mfma_f32_16x16x32_bf16(a1u.v, vf1[vs], oacc[vs], 0, 0, 0);
  }
}

__device__ __forceinline__ void fa_store(float lrun, f32x4 (&oacc)[4],
    const int b, const int qrow0, const int h, const int m, const int quad,
    __hip_bfloat16* __restrict__ aout)
{
  float lr[4];
  #pragma unroll
  for (int r = 0; r < 4; r++) lr[r] = __shfl(lrun, (quad << 2) | r, 64);
  #pragma unroll
  for (int vs = 0; vs < 4; vs++)
    #pragma unroll
    for (int r = 0; r < 4; r++)
      aout[(size_t)(b*T_ + qrow0 + quad*4 + r) * 1024 + h*64 + vs*16 + m]
          = __float2bfloat16(oacc[vs][r] / lr[r]);
}

// Pair-balanced MFMA flash attention: block x handles q-tiles x and 31-x of one
// (b,h) => every block = 33 compute-tiles (no tail). K (8KB) + V^T (8KB) staged
// in LDS once per key-tile via global_load_lds (XOR-swizzled slots, frag reads
// 2-way = free); all 4 waves and both q-states share the staged tile.
__global__ __launch_bounds__(256)
void attn_pair(const __hip_bfloat16* __restrict__ qb,
               const __hip_bfloat16* __restrict__ kvb16,
               const __hip_bfloat16* __restrict__ krope16,
               const __hip_bfloat16* __restrict__ vt16,
               __hip_bfloat16* __restrict__ aout)
{
  __shared__ __hip_bfloat16 Kl[64*64];   // [key][dblk swizzled] 8 KB
  __shared__ __hip_bfloat16 Vl[64*64];   // [d][kblk swizzled]  8 KB
  const int tid = threadIdx.x;
  const int wv = tid >> 6, lane = tid & 63;
  const int m = lane & 15, quad = lane >> 4;
  const int ta = blockIdx.x;            // 0..15
  const int tb = 31 - blockIdx.x;       // 16..31
  const int bh = blockIdx.y;
  const int b = bh >> 4, h = bh & 15;
  const int qa = ta*64 + wv*16;         // state A wave query base
  const int qbq = tb*64 + wv*16;        // state B wave query base

  // Q fragments, both states
  const __hip_bfloat16* qra = qb + ((size_t)bh*T_ + qa + m)*64 + quad*8;
  const bf16x8 qA0 = *(const bf16x8*)qra, qA1 = *(const bf16x8*)(qra + 32);
  const __hip_bfloat16* qrb = qb + ((size_t)bh*T_ + qbq + m)*64 + quad*8;
  const bf16x8 qB0 = *(const bf16x8*)qrb, qB1 = *(const bf16x8*)(qrb + 32);

  // staging source pointers (per lane, advanced per tile)
  const __hip_bfloat16* pK[2]; size_t incK[2];
  const __hip_bfloat16* pV[2];
  #pragma unroll
  for (int r = 0; r < 2; r++) {
    const int slot = r*256 + tid;
    const int key = slot >> 3, dblk = slot & 7;
    const int de = dblk ^ (key & 7);
    if (de < 6) { pK[r] = kvb16 + ((size_t)(b*T_ + key)*1792 + h*112 + de*8); incK[r] = (size_t)64*1792; }
    else        { pK[r] = krope16 + ((size_t)(b*T_ + key)*16 + (de-6)*8);     incK[r] = (size_t)64*16; }
    const int drow = slot >> 3, kblk = slot & 7;
    pV[r] = vt16 + ((size_t)bh*64 + drow)*T_ + ((kblk ^ (drow & 7)) << 3);
  }

  f32x4 oA[4], oB[4];
  #pragma unroll
  for (int vs = 0; vs < 4; vs++) { oA[vs] = (f32x4){0.f,0.f,0.f,0.f}; oB[vs] = (f32x4){0.f,0.f,0.f,0.f}; }
  float mA = -3.0e38f, lA = 0.f, mB = -3.0e38f, lB = 0.f;

  const int sw = quad ^ (m & 7);        // swizzled slot for low half frags

  for (int kt = 0; kt <= tb; kt++) {
    const int k0 = kt << 6;
    // ---- stage K and V^T (16 KB total) ----
    #pragma unroll
    for (int r = 0; r < 2; r++) {
      gload_lds16(pK[r], Kl + (r*256 + wv*64)*8);
      gload_lds16(pV[r], Vl + (r*256 + wv*64)*8);
      pK[r] += incK[r]; pV[r] += 64;
    }
    __syncthreads();

    // ---- V frags (shared by both states) ----
    bf16x8 vf0[4], vf1[4];
    #pragma unroll
    for (int vs = 0; vs < 4; vs++) {
      vf0[vs] = *(const bf16x8*)(Vl + (vs*16 + m)*64 + sw*8);
      vf1[vs] = *(const bf16x8*)(Vl + (vs*16 + m)*64 + (sw^4)*8);
    }

    // ---- S^T via shared K frags ----
    const bool doA = (kt <= ta);
    f32x4 sA[4], sB[4];
    #pragma unroll
    for (int sub = 0; sub < 4; sub++) {
      const bf16x8 kf0 = *(const bf16x8*)(Kl + (sub*16 + m)*64 + sw*8);
      const bf16x8 kf1 = *(const bf16x8*)(Kl + (sub*16 + m)*64 + (sw^4)*8);
      f32x4 z = (f32x4){0.f,0.f,0.f,0.f};
      z = __builtin_amdgcn_mfma_f32_16x16x32_bf16(kf0, qB0, z, 0, 0, 0);
      z = __builtin_amdgcn_mfma_f32_16x16x32_bf16(kf1, qB1, z, 0, 0, 0);
      sB[sub] = z;
      if (doA) {
        f32x4 y = (f32x4){0.f,0.f,0.f,0.f};
        y = __builtin_amdgcn_mfma_f32_16x16x32_bf16(kf0, qA0, y, 0, 0, 0);
        y = __builtin_amdgcn_mfma_f32_16x16x32_bf16(kf1, qA1, y, 0, 0, 0);
        sA[sub] = y;
      }
    }

    if (doA) fa_update(sA, kt == ta, k0, qa + m, m, quad, mA, lA, oA, vf0, vf1);
    fa_update(sB, kt == tb, k0, qbq + m, m, quad, mB, lB, oB, vf0, vf1);
    __syncthreads();
  }

  fa_store(lA, oA, b, qa, h, m, quad, aout);
  fa_store(lB, oB, b, qbq, h, m, quad, aout);
}

extern "C" void kernel_launch(void* const* d_in, const int* in_sizes, int n_in,
                              void* d_out, int out_size, void* d_ws, size_t ws_size,
                              hipStream_t stream)
{
  const float* x    = (const float*)d_in[0];
  const float* cosp = (const float*)d_in[1];
  const float* sinp = (const float*)d_in[2];
  const float* Wq   = (const float*)d_in[3];
  const float* qw   = (const float*)d_in[4];
  const float* Wkva = (const float*)d_in[5];
  const float* kw   = (const float*)d_in[6];
  const float* Wkvb = (const float*)d_in[7];
  const float* Wo   = (const float*)d_in[8];
  float* out = (float*)d_out;

  float* q     = (float*)d_ws;                         // 4,194,304 f (ab16 alias later)
  float* kva   = q + 4194304;                          //   589,824 f
  __hip_bfloat16* kvb16   = (__hip_bfloat16*)(kva + 589824);  // 7,340,032 (xb16 alias first)
  __hip_bfloat16* kvl16   = kvb16 + 7340032;           //   524,288
  __hip_bfloat16* qb16    = kvl16 + 524288;            // 4,194,304
  __hip_bfloat16* vt16    = qb16 + 4194304;            // 4,194,304
  __hip_bfloat16* krope16 = vt16 + 4194304;            //    65,536
  __hip_bfloat16* Wqb     = krope16 + 65536;           // 1,048,576
  __hip_bfloat16* Wkvab   = Wqb + 1048576;             //   147,456
  __hip_bfloat16* Wkvbb   = Wkvab + 147456;            //   229,376
  __hip_bfloat16* Wob     = Wkvbb + 229376;            // 1,048,576
  __hip_bfloat16* xb16    = kvb16;                     // alias: dead before kvb16 written
  __hip_bfloat16* ab16    = (__hip_bfloat16*)q;        // alias: q dead before attn writes

  const int M = B_ * T_;   // 4096

  cvt5<<<6512, 256, 0, stream>>>(x, Wq, Wkva, Wkvb, Wo, xb16, Wqb, Wkvab, Wkvbb, Wob);
  gemm_bt<float><<<dim3(8, 32), 256, 0, stream>>>(xb16, Wqb, q, M, 1024, 1024);
  gemm_bt<float><<<dim3(2, 32), 256, 0, stream>>>(xb16, Wkvab, kva, M, 144, 1024);
  prep_q<<<M * NH, 64, 0, stream>>>(q, qw, cosp, sinp, qb16);
  prep_kv<<<M, 128, 0, stream>>>(kva, kw, cosp, sinp, kvl16, krope16);
  gemm_bt<__hip_bfloat16><<<dim3(14, 32), 256, 0, stream>>>(kvl16, Wkvbb, kvb16, M, 1792, 128);
  pack_v<<<dim3(T_/64, B_ * NH), 256, 0, stream>>>(kvb16, vt16);
  attn_pair<<<dim3(16, B_ * NH), 256, 0, stream>>>(qb16, kvb16, krope16, vt16, ab16);
  gemm_bt<float><<<dim3(8, 32), 256, 0, stream>>>(ab16, Wob, out, M, 1024, 1024);
}

// Round 7
// 209.721 us; speedup vs baseline: 46.4296x; 1.1954x over previous
//
#include <hip/hip_runtime.h>
#include <hip/hip_bf16.h>
#include <math.h>

#define NH 16
#define T_ 2048
#define B_ 2
#define D_ 1024
#define EPS 1e-6f

typedef __attribute__((ext_vector_type(8))) short bf16x8;
typedef __attribute__((ext_vector_type(4))) float f32x4;

__device__ __forceinline__ float wred_sum(float v){
  #pragma unroll
  for (int o = 32; o > 0; o >>= 1) v += __shfl_xor(v, o, 64);
  return v;
}

__device__ __forceinline__ unsigned pack_bf16(float a, float b){
  __hip_bfloat162 t = __float22bfloat162_rn(make_float2(a, b));
  unsigned r; __builtin_memcpy(&r, &t, 4); return r;
}

__device__ __forceinline__ void gload_lds16(const void* g, void* l){
  __builtin_amdgcn_global_load_lds((const __attribute__((address_space(1))) void*)g,
                                   (__attribute__((address_space(3))) void*)l, 16, 0, 0);
}

// ---- convert x + all weights to bf16 in one pass (float4-indexed segments) ----
__global__ __launch_bounds__(256)
void cvt5(const float* __restrict__ x, const float* __restrict__ wq,
          const float* __restrict__ wkva, const float* __restrict__ wkvb,
          const float* __restrict__ wo,
          __hip_bfloat16* __restrict__ xb, __hip_bfloat16* __restrict__ wqb,
          __hip_bfloat16* __restrict__ wkvab, __hip_bfloat16* __restrict__ wkvbb,
          __hip_bfloat16* __restrict__ wob)
{
  const int i = blockIdx.x * 256 + threadIdx.x;     // float4 index, 1,667,072 total
  const float* s; __hip_bfloat16* d; int off;
  if      (i < 1048576) { s = x;    d = xb;    off = i; }
  else if (i < 1310720) { s = wq;   d = wqb;   off = i - 1048576; }
  else if (i < 1347584) { s = wkva; d = wkvab; off = i - 1310720; }
  else if (i < 1404928) { s = wkvb; d = wkvbb; off = i - 1347584; }
  else                  { s = wo;   d = wob;   off = i - 1404928; }
  float4 v = *(const float4*)(s + (size_t)off * 4);
  *(__hip_bfloat162*)(d + (size_t)off * 4)     = __float22bfloat162_rn(make_float2(v.x, v.y));
  *(__hip_bfloat162*)(d + (size_t)off * 4 + 2) = __float22bfloat162_rn(make_float2(v.z, v.w));
}

// ---- bf16 MFMA GEMM, 128x64 tile, 4 waves each 32x64 ----
template<typename CT>
__global__ __launch_bounds__(256, 2)
void gemm_bt64(const __hip_bfloat16* __restrict__ A, const __hip_bfloat16* __restrict__ W,
               CT* __restrict__ C, int M, int N, int K)
{
  __shared__ __hip_bfloat16 As[128 * 64];   // 16 KB
  __shared__ __hip_bfloat16 Ws[64 * 64];    // 8 KB
  const int tid = threadIdx.x;
  const int wv = tid >> 6, lane = tid & 63;
  const int m = lane & 15, quad = lane >> 4;
  const int bm = blockIdx.y * 128, bn = blockIdx.x * 64;

  const __hip_bfloat16* ga[4];
  const __hip_bfloat16* gw[2];
  #pragma unroll
  for (int i = 0; i < 4; i++) {
    const int slot = i*256 + tid;
    const int row = slot >> 3, cb = slot & 7;
    ga[i] = A + (size_t)(bm + row) * K + ((cb ^ (row & 7)) << 3);
  }
  #pragma unroll
  for (int i = 0; i < 2; i++) {
    const int slot = i*256 + tid;
    const int row = slot >> 3, cb = slot & 7;
    int wr = bn + row; if (wr >= N) wr = N - 1;
    gw[i] = W + (size_t)wr * K + ((cb ^ (row & 7)) << 3);
  }

  f32x4 acc[2][4];
  #pragma unroll
  for (int mi = 0; mi < 2; mi++)
    #pragma unroll
    for (int nj = 0; nj < 4; nj++) acc[mi][nj] = (f32x4){0.f,0.f,0.f,0.f};

  for (int k0 = 0; k0 < K; k0 += 64) {
    #pragma unroll
    for (int i = 0; i < 4; i++) {
      gload_lds16(ga[i], As + (i*256 + wv*64)*8);
      ga[i] += 64;
    }
    #pragma unroll
    for (int i = 0; i < 2; i++) {
      gload_lds16(gw[i], Ws + (i*256 + wv*64)*8);
      gw[i] += 64;
    }
    __syncthreads();
    #pragma unroll
    for (int ks = 0; ks < 2; ks++) {
      const int cb = ((ks*4 + quad) ^ (m & 7)) << 3;
      bf16x8 af[2], wf[4];
      #pragma unroll
      for (int mi = 0; mi < 2; mi++)
        af[mi] = *(const bf16x8*)(As + (wv*32 + mi*16 + m) * 64 + cb);
      #pragma unroll
      for (int nj = 0; nj < 4; nj++)
        wf[nj] = *(const bf16x8*)(Ws + (nj*16 + m) * 64 + cb);
      #pragma unroll
      for (int mi = 0; mi < 2; mi++)
        #pragma unroll
        for (int nj = 0; nj < 4; nj++)
          acc[mi][nj] = __builtin_amdgcn_mfma_f32_16x16x32_bf16(af[mi], wf[nj], acc[mi][nj], 0, 0, 0);
    }
    __syncthreads();
  }

  #pragma unroll
  for (int mi = 0; mi < 2; mi++)
    #pragma unroll
    for (int nj = 0; nj < 4; nj++) {
      const int col = bn + nj*16 + m;
      if (col < N) {
        #pragma unroll
        for (int r = 0; r < 4; r++) {
          const int row = bm + wv*32 + mi*16 + quad*4 + r;
          if constexpr (sizeof(CT) == 2)
            C[(size_t)row * N + col] = (CT)__float2bfloat16(acc[mi][nj][r]);
          else
            C[(size_t)row * N + col] = acc[mi][nj][r];
        }
      }
    }
}

// ---- Wq GEMM with fused RMSNorm(64)+qw+RoPE epilogue -> qb16[b,h,t,64]*0.125 ----
__global__ __launch_bounds__(256, 2)
void gemm_q_fused(const __hip_bfloat16* __restrict__ A, const __hip_bfloat16* __restrict__ W,
                  const float* __restrict__ qw, const float* __restrict__ cosp,
                  const float* __restrict__ sinp, __hip_bfloat16* __restrict__ qb)
{
  __shared__ __hip_bfloat16 As[128 * 64];
  __shared__ __hip_bfloat16 Ws[64 * 64];
  const int K = 1024;
  const int tid = threadIdx.x;
  const int wv = tid >> 6, lane = tid & 63;
  const int m = lane & 15, quad = lane >> 4;
  const int bm = blockIdx.y * 128;
  const int head = blockIdx.x;               // 0..15
  const int bn = head * 64;

  const __hip_bfloat16* ga[4];
  const __hip_bfloat16* gw[2];
  #pragma unroll
  for (int i = 0; i < 4; i++) {
    const int slot = i*256 + tid;
    const int row = slot >> 3, cb = slot & 7;
    ga[i] = A + (size_t)(bm + row) * K + ((cb ^ (row & 7)) << 3);
  }
  #pragma unroll
  for (int i = 0; i < 2; i++) {
    const int slot = i*256 + tid;
    const int row = slot >> 3, cb = slot & 7;
    gw[i] = W + (size_t)(bn + row) * K + ((cb ^ (row & 7)) << 3);
  }

  f32x4 acc[2][4];
  #pragma unroll
  for (int mi = 0; mi < 2; mi++)
    #pragma unroll
    for (int nj = 0; nj < 4; nj++) acc[mi][nj] = (f32x4){0.f,0.f,0.f,0.f};

  for (int k0 = 0; k0 < K; k0 += 64) {
    #pragma unroll
    for (int i = 0; i < 4; i++) { gload_lds16(ga[i], As + (i*256 + wv*64)*8); ga[i] += 64; }
    #pragma unroll
    for (int i = 0; i < 2; i++) { gload_lds16(gw[i], Ws + (i*256 + wv*64)*8); gw[i] += 64; }
    __syncthreads();
    #pragma unroll
    for (int ks = 0; ks < 2; ks++) {
      const int cb = ((ks*4 + quad) ^ (m & 7)) << 3;
      bf16x8 af[2], wf[4];
      #pragma unroll
      for (int mi = 0; mi < 2; mi++)
        af[mi] = *(const bf16x8*)(As + (wv*32 + mi*16 + m) * 64 + cb);
      #pragma unroll
      for (int nj = 0; nj < 4; nj++)
        wf[nj] = *(const bf16x8*)(Ws + (nj*16 + m) * 64 + cb);
      #pragma unroll
      for (int mi = 0; mi < 2; mi++)
        #pragma unroll
        for (int nj = 0; nj < 4; nj++)
          acc[mi][nj] = __builtin_amdgcn_mfma_f32_16x16x32_bf16(af[mi], wf[nj], acc[mi][nj], 0, 0, 0);
    }
    __syncthreads();
  }

  float qwv[4];
  #pragma unroll
  for (int nj = 0; nj < 4; nj++) qwv[nj] = qw[nj*16 + m];
  const int j = m & 7;
  #pragma unroll
  for (int mi = 0; mi < 2; mi++) {
    #pragma unroll
    for (int r = 0; r < 4; r++) {
      float ss = 0.f;
      #pragma unroll
      for (int nj = 0; nj < 4; nj++) { const float t = acc[mi][nj][r]; ss = fmaf(t, t, ss); }
      ss += __shfl_xor(ss, 1, 64); ss += __shfl_xor(ss, 2, 64);
      ss += __shfl_xor(ss, 4, 64); ss += __shfl_xor(ss, 8, 64);
      const float nrm = rsqrtf(ss * (1.0f/64.0f) + EPS);
      float v[4];
      #pragma unroll
      for (int nj = 0; nj < 4; nj++) v[nj] = acc[mi][nj][r] * nrm * qwv[nj];
      const int grow = bm + wv*32 + mi*16 + quad*4 + r;
      const int t = grow & (T_ - 1);
      const int b = grow >> 11;
      const float part = __shfl_xor(v[3], 8, 64);
      const float c = cosp[t*8 + j], sn = sinp[t*8 + j];
      v[3] = (m < 8) ? (v[3]*c - part*sn) : (v[3]*c + part*sn);
      __hip_bfloat16* dst = qb + ((size_t)(b*NH + head)*T_ + t)*64 + m;
      #pragma unroll
      for (int nj = 0; nj < 4; nj++) dst[nj*16] = __float2bfloat16(v[nj] * 0.125f);
    }
  }
}

// Per (b,t): RMSNorm over kv_a[:128] -> kvl16 (bf16); RoPE on kv_a[128:144] -> krope16 (bf16).
__global__ void prep_kv(const float* __restrict__ kva, const float* __restrict__ kw,
                        const float* __restrict__ cosp, const float* __restrict__ sinp,
                        __hip_bfloat16* __restrict__ kvl16, __hip_bfloat16* __restrict__ krope16)
{
  const int tid = threadIdx.x;   // 0..127
  const int bt = blockIdx.x;
  const int t = bt % T_;
  const float* row = kva + (size_t)bt * 144;
  const float v = row[tid];
  float s = wred_sum(v * v);
  __shared__ float red[2];
  if ((tid & 63) == 0) red[tid >> 6] = s;
  __syncthreads();
  const float total = red[0] + red[1];
  const float norm = rsqrtf(total * (1.0f/128.0f) + EPS);
  kvl16[(size_t)bt * 128 + tid] = __float2bfloat16(v * norm * kw[tid]);
  if (tid < 16) {
    const int j = tid & 7;
    const float c = cosp[t*8 + j], sn = sinp[t*8 + j];
    const float x1 = row[128 + j], x2 = row[136 + j];
    krope16[(size_t)bt * 16 + tid] = __float2bfloat16((tid < 8) ? (x1 * c - x2 * sn)
                                                               : (x2 * c + x1 * sn));
  }
}

// vt16[b,h,d,t] = V transposed (V = kvb16 cols 48..111 of head h).
__global__ __launch_bounds__(256)
void pack_v(const __hip_bfloat16* __restrict__ kvb16, __hip_bfloat16* __restrict__ vt)
{
  __shared__ short Vl[64][72];
  const int tid = threadIdx.x;
  const int t0 = blockIdx.x * 64;
  const int bh = blockIdx.y;
  const int b = bh >> 4, h = bh & 15;
  const int r = tid >> 2, c = tid & 3;
  {
    const short* src = (const short*)(kvb16 + ((size_t)(b*T_ + t0 + r)*1792 + h*112 + 48 + c*16));
    union { bf16x8 v; short e[8]; } u0, u1;
    u0.v = *(const bf16x8*)src;
    u1.v = *(const bf16x8*)(src + 8);
    #pragma unroll
    for (int jj = 0; jj < 8; jj++) { Vl[r][c*16+jj] = u0.e[jj]; Vl[r][c*16+8+jj] = u1.e[jj]; }
  }
  __syncthreads();
  const int d = tid >> 2, tq = tid & 3;
  union { bf16x8 v; short e[8]; } o0, o1;
  #pragma unroll
  for (int jj = 0; jj < 8; jj++) { o0.e[jj] = Vl[tq*16+jj][d]; o1.e[jj] = Vl[tq*16+8+jj][d]; }
  short* dst = (short*)(vt + ((size_t)bh*64 + d)*T_ + t0 + tq*16);
  *(bf16x8*)dst = o0.v;
  *(bf16x8*)(dst + 8) = o1.v;
}

// ---- softmax update for one state over a 128-key tile; produces PV A-frags ----
__device__ __forceinline__ void fa_softmax(f32x4 (&s)[8], const bool diag,
    const int k0, const int qglob, const int m, const int quad,
    float& mrun, float& lrun, f32x4 (&o)[4], bf16x8 (&a)[4])
{
  if (diag) {
    #pragma unroll
    for (int sub = 0; sub < 8; sub++)
      #pragma unroll
      for (int r = 0; r < 4; r++)
        if (k0 + sub*16 + quad*4 + r > qglob) s[sub][r] = -1e30f;
  }
  float tm = -3.0e38f;
  #pragma unroll
  for (int sub = 0; sub < 8; sub++)
    #pragma unroll
    for (int r = 0; r < 4; r++) tm = fmaxf(tm, s[sub][r]);
  tm = fmaxf(tm, __shfl_xor(tm, 16, 64));
  tm = fmaxf(tm, __shfl_xor(tm, 32, 64));
  const float mn = fmaxf(mrun, tm);
  const float alpha = __expf(mrun - mn);
  float rs = 0.f;
  float p[8][4];
  #pragma unroll
  for (int sub = 0; sub < 8; sub++)
    #pragma unroll
    for (int r = 0; r < 4; r++) {
      const float e = __expf(s[sub][r] - mn);
      p[sub][r] = e; rs += e;
    }
  rs += __shfl_xor(rs, 16, 64);
  rs += __shfl_xor(rs, 32, 64);
  lrun = lrun * alpha + rs;
  mrun = mn;

  unsigned u[8][2];
  #pragma unroll
  for (int sub = 0; sub < 8; sub++) {
    u[sub][0] = pack_bf16(p[sub][0], p[sub][1]);
    u[sub][1] = pack_bf16(p[sub][2], p[sub][3]);
  }
  // Transpose: dest lane (quad,m) frag c word w4 = keys c*32 + quad*8 + 2*w4 + {0,1}.
  // Shuffle BOTH sub-words, select with DEST quad after (source-lane quad differs!).
  #pragma unroll
  for (int c = 0; c < 4; c++) {
    union { int i[4]; bf16x8 v; } au;
    #pragma unroll
    for (int w4 = 0; w4 < 4; w4++) {
      const int src = (((2*quad + (w4 >> 1)) & 3) << 4) | m;
      const int lo = __shfl((int)u[c*2][w4 & 1], src, 64);
      const int hi = __shfl((int)u[c*2+1][w4 & 1], src, 64);
      au.i[w4] = (quad & 2) ? hi : lo;
    }
    a[c] = au.v;
  }

  float al[4];
  #pragma unroll
  for (int r = 0; r < 4; r++) al[r] = __shfl(alpha, (quad << 2) | r, 64);
  #pragma unroll
  for (int vs = 0; vs < 4; vs++)
    #pragma unroll
    for (int r = 0; r < 4; r++) o[vs][r] *= al[r];
}

__device__ __forceinline__ void fa_store(float lrun, f32x4 (&oacc)[4],
    const int b, const int qrow0, const int h, const int m, const int quad,
    __hip_bfloat16* __restrict__ aout)
{
  float lr[4];
  #pragma unroll
  for (int r = 0; r < 4; r++) lr[r] = __shfl(lrun, (quad << 2) | r, 64);
  #pragma unroll
  for (int vs = 0; vs < 4; vs++)
    #pragma unroll
    for (int r = 0; r < 4; r++)
      aout[(size_t)(b*T_ + qrow0 + quad*4 + r) * 1024 + h*64 + vs*16 + m]
          = __float2bfloat16(oacc[vs][r] / lr[r]);
}

// Pair-balanced MFMA flash attention, BK=128, double-buffered LDS staging.
__global__ __launch_bounds__(256, 2)
void attn_pair2(const __hip_bfloat16* __restrict__ qb,
                const __hip_bfloat16* __restrict__ kvb16,
                const __hip_bfloat16* __restrict__ krope16,
                const __hip_bfloat16* __restrict__ vt16,
                __hip_bfloat16* __restrict__ aout)
{
  __shared__ __hip_bfloat16 SL[32768];   // K: [buf][128][64] @0/8192; V: [buf][64][128] @16384/24576
  const int tid = threadIdx.x;
  const int wv = tid >> 6, lane = tid & 63;
  const int m = lane & 15, quad = lane >> 4;
  const int ta = blockIdx.x;            // 0..15
  const int tb = 31 - ta;               // 16..31
  const int bh = blockIdx.y;
  const int b = bh >> 4, h = bh & 15;
  const int qbaseA = ta*64 + wv*16;
  const int qbaseB = tb*64 + wv*16;
  const int ntA = (ta + 2) >> 1;
  const int ntB = (tb + 2) >> 1;

  const __hip_bfloat16* qra = qb + ((size_t)bh*T_ + qbaseA + m)*64 + quad*8;
  const bf16x8 qA0 = *(const bf16x8*)qra, qA1 = *(const bf16x8*)(qra + 32);
  const __hip_bfloat16* qrb = qb + ((size_t)bh*T_ + qbaseB + m)*64 + quad*8;
  const bf16x8 qB0 = *(const bf16x8*)qrb, qB1 = *(const bf16x8*)(qrb + 32);

  const __hip_bfloat16* pK[4]; size_t iK[4];
  const __hip_bfloat16* pV[4];
  #pragma unroll
  for (int i = 0; i < 4; i++) {
    const int slot = i*256 + tid;
    const int krow = slot >> 3;
    const int kde = (slot & 7) ^ (krow & 7);
    if (kde < 6) { pK[i] = kvb16 + (size_t)(b*T_ + krow)*1792 + h*112 + kde*8; iK[i] = (size_t)128*1792; }
    else         { pK[i] = krope16 + (size_t)(b*T_ + krow)*16 + (kde-6)*8;     iK[i] = (size_t)128*16; }
    const int vd = slot >> 4;
    const int vde = (slot & 15) ^ (vd & 7);
    pV[i] = vt16 + ((size_t)bh*64 + vd)*T_ + vde*8;
  }

  auto stage = [&](int buf){
    #pragma unroll
    for (int i = 0; i < 4; i++) {
      gload_lds16(pK[i], SL + buf*8192 + (i*256 + wv*64)*8);
      gload_lds16(pV[i], SL + 16384 + buf*8192 + (i*256 + wv*64)*8);
      pK[i] += iK[i]; pV[i] += 128;
    }
  };

  f32x4 oA[4], oB[4];
  #pragma unroll
  for (int vs = 0; vs < 4; vs++) { oA[vs] = (f32x4){0.f,0.f,0.f,0.f}; oB[vs] = (f32x4){0.f,0.f,0.f,0.f}; }
  float mA = -3.0e38f, lA = 0.f, mB = -3.0e38f, lB = 0.f;

  const int sw0 = quad ^ (m & 7);
  stage(0);

  for (int kt = 0; kt < ntB; kt++) {
    const int cur = kt & 1;
    __syncthreads();
    const __hip_bfloat16* Kc = SL + cur*8192;
    const __hip_bfloat16* Vc = SL + 16384 + cur*8192;
    const bool doA = (kt < ntA);

    f32x4 sA[8], sB[8];
    #pragma unroll
    for (int sub = 0; sub < 8; sub++) {
      const bf16x8 kf0 = *(const bf16x8*)(Kc + (sub*16 + m)*64 + sw0*8);
      const bf16x8 kf1 = *(const bf16x8*)(Kc + (sub*16 + m)*64 + (sw0^4)*8);
      f32x4 z = (f32x4){0.f,0.f,0.f,0.f};
      z = __builtin_amdgcn_mfma_f32_16x16x32_bf16(kf0, qB0, z, 0, 0, 0);
      z = __builtin_amdgcn_mfma_f32_16x16x32_bf16(kf1, qB1, z, 0, 0, 0);
      sB[sub] = z;
      if (doA) {
        f32x4 y = (f32x4){0.f,0.f,0.f,0.f};
        y = __builtin_amdgcn_mfma_f32_16x16x32_bf16(kf0, qA0, y, 0, 0, 0);
        y = __builtin_amdgcn_mfma_f32_16x16x32_bf16(kf1, qA1, y, 0, 0, 0);
        sA[sub] = y;
      }
    }

    if (kt + 1 < ntB) stage(cur ^ 1);

    bf16x8 aA[4], aB[4];
    fa_softmax(sB, kt == ntB-1, kt*128, qbaseB + m, m, quad, mB, lB, oB, aB);
    if (doA) fa_softmax(sA, kt == ntA-1, kt*128, qbaseA + m, m, quad, mA, lA, oA, aA);

    #pragma unroll
    for (int vs = 0; vs < 4; vs++) {
      #pragma unroll
      for (int c = 0; c < 4; c++) {
        const bf16x8 vf = *(const bf16x8*)(Vc + (vs*16 + m)*128 + (((c*4 + quad) ^ (m & 7)) << 3));
        oB[vs] = __builtin_amdgcn_mfma_f32_16x16x32_bf16(aB[c], vf, oB[vs], 0, 0, 0);
        if (doA) oA[vs] = __builtin_amdgcn_mfma_f32_16x16x32_bf16(aA[c], vf, oA[vs], 0, 0, 0);
      }
    }
  }

  fa_store(lA, oA, b, qbaseA, h, m, quad, aout);
  fa_store(lB, oB, b, qbaseB, h, m, quad, aout);
}

extern "C" void kernel_launch(void* const* d_in, const int* in_sizes, int n_in,
                              void* d_out, int out_size, void* d_ws, size_t ws_size,
                              hipStream_t stream)
{
  const float* x    = (const float*)d_in[0];
  const float* cosp = (const float*)d_in[1];
  const float* sinp = (const float*)d_in[2];
  const float* Wq   = (const float*)d_in[3];
  const float* qw   = (const float*)d_in[4];
  const float* Wkva = (const float*)d_in[5];
  const float* kw   = (const float*)d_in[6];
  const float* Wkvb = (const float*)d_in[7];
  const float* Wo   = (const float*)d_in[8];
  float* out = (float*)d_out;

  float* kva = (float*)d_ws;                                  //   589,824 f
  __hip_bfloat16* kvb16   = (__hip_bfloat16*)(kva + 589824);  // 7,340,032 (xb16 alias first)
  __hip_bfloat16* kvl16   = kvb16 + 7340032;                  //   524,288
  __hip_bfloat16* qb16    = kvl16 + 524288;                   // 4,194,304
  __hip_bfloat16* vt16    = qb16 + 4194304;                   // 4,194,304
  __hip_bfloat16* krope16 = vt16 + 4194304;                   //    65,536
  __hip_bfloat16* Wqb     = krope16 + 65536;                  // 1,048,576
  __hip_bfloat16* Wkvab   = Wqb + 1048576;                    //   147,456
  __hip_bfloat16* Wkvbb   = Wkvab + 147456;                   //   229,376
  __hip_bfloat16* Wob     = Wkvbb + 229376;                   // 1,048,576
  __hip_bfloat16* ab16    = Wob + 1048576;                    // 4,194,304
  __hip_bfloat16* xb16    = kvb16;   // alias: dead before kvb16 written

  const int M = B_ * T_;   // 4096

  cvt5<<<6512, 256, 0, stream>>>(x, Wq, Wkva, Wkvb, Wo, xb16, Wqb, Wkvab, Wkvbb, Wob);
  gemm_q_fused<<<dim3(16, 32), 256, 0, stream>>>(xb16, Wqb, qw, cosp, sinp, qb16);
  gemm_bt64<float><<<dim3(3, 32), 256, 0, stream>>>(xb16, Wkvab, kva, M, 144, 1024);
  prep_kv<<<M, 128, 0, stream>>>(kva, kw, cosp, sinp, kvl16, krope16);
  gemm_bt64<__hip_bfloat16><<<dim3(28, 32), 256, 0, stream>>>(kvl16, Wkvbb, kvb16, M, 1792, 128);
  pack_v<<<dim3(T_/64, B_ * NH), 256, 0, stream>>>(kvb16, vt16);
  attn_pair2<<<dim3(16, B_ * NH), 256, 0, stream>>>(qb16, kvb16, krope16, vt16, ab16);
  gemm_bt64<float><<<dim3(16, 32), 256, 0, stream>>>(ab16, Wob, out, M, 1024, 1024);
}

// Round 8
// 190.776 us; speedup vs baseline: 51.0403x; 1.0993x over previous
//
#include <hip/hip_runtime.h>
#include <hip/hip_bf16.h>
#include <math.h>

#define NH 16
#define T_ 2048
#define B_ 2
#define D_ 1024
#define EPS 1e-6f

typedef __attribute__((ext_vector_type(8))) short bf16x8;
typedef __attribute__((ext_vector_type(4))) float f32x4;

__device__ __forceinline__ float wred_sum(float v){
  #pragma unroll
  for (int o = 32; o > 0; o >>= 1) v += __shfl_xor(v, o, 64);
  return v;
}

__device__ __forceinline__ unsigned pack_bf16(float a, float b){
  __hip_bfloat162 t = __float22bfloat162_rn(make_float2(a, b));
  unsigned r; __builtin_memcpy(&r, &t, 4); return r;
}

__device__ __forceinline__ void gload_lds16(const void* g, void* l){
  __builtin_amdgcn_global_load_lds((const __attribute__((address_space(1))) void*)g,
                                   (__attribute__((address_space(3))) void*)l, 16, 0, 0);
}

// ---- convert x + weights to bf16; Wkvb rows PERMUTED: [h*48+d | 768+h*64+dv] ----
__global__ __launch_bounds__(256)
void cvt5(const float* __restrict__ x, const float* __restrict__ wq,
          const float* __restrict__ wkva, const float* __restrict__ wkvb,
          const float* __restrict__ wo,
          __hip_bfloat16* __restrict__ xb, __hip_bfloat16* __restrict__ wqb,
          __hip_bfloat16* __restrict__ wkvab, __hip_bfloat16* __restrict__ wkvbb,
          __hip_bfloat16* __restrict__ wob)
{
  const int i = blockIdx.x * 256 + threadIdx.x;     // float4 index, 1,667,072 total
  const float* s; __hip_bfloat16* d; size_t soff, doff;
  if      (i < 1048576) { s = x;    d = xb;    soff = doff = i; }
  else if (i < 1310720) { s = wq;   d = wqb;   soff = doff = i - 1048576; }
  else if (i < 1347584) { s = wkva; d = wkvab; soff = doff = i - 1310720; }
  else if (i < 1404928) {
    const int off = i - 1347584;                    // float4 idx into 1792x128
    const int srow = off >> 5, c4 = off & 31;
    const int h = srow / 112, dd = srow % 112;
    const int drow = (dd < 48) ? (h*48 + dd) : (768 + h*64 + (dd - 48));
    s = wkvb; d = wkvbb; soff = off; doff = (size_t)drow*32 + c4;
  }
  else                  { s = wo;   d = wob;   soff = doff = i - 1404928; }
  float4 v = *(const float4*)(s + soff * 4);
  *(__hip_bfloat162*)(d + doff * 4)     = __float22bfloat162_rn(make_float2(v.x, v.y));
  *(__hip_bfloat162*)(d + doff * 4 + 2) = __float22bfloat162_rn(make_float2(v.z, v.w));
}

// ---- bf16 MFMA GEMM, 128x64 tile, DOUBLE-BUFFERED staging (48KB LDS) ----
// order per iter: sync(cur ready) -> issue stage(next) -> compute(cur):
// the barrier's vmcnt(0) then drains loads that had a full compute phase.
template<typename CT>
__global__ __launch_bounds__(256, 2)
void gemm_bt64(const __hip_bfloat16* __restrict__ A, const __hip_bfloat16* __restrict__ W,
               CT* __restrict__ C, int M, int N, int K)
{
  __shared__ __hip_bfloat16 As[2][128 * 64];   // 32 KB
  __shared__ __hip_bfloat16 Ws[2][64 * 64];    // 16 KB
  const int tid = threadIdx.x;
  const int wv = tid >> 6, lane = tid & 63;
  const int m = lane & 15, quad = lane >> 4;
  const int bm = blockIdx.y * 128, bn = blockIdx.x * 64;

  const __hip_bfloat16* ga[4];
  const __hip_bfloat16* gw[2];
  #pragma unroll
  for (int i = 0; i < 4; i++) {
    const int slot = i*256 + tid;
    const int row = slot >> 3, cb = slot & 7;
    ga[i] = A + (size_t)(bm + row) * K + ((cb ^ (row & 7)) << 3);
  }
  #pragma unroll
  for (int i = 0; i < 2; i++) {
    const int slot = i*256 + tid;
    const int row = slot >> 3, cb = slot & 7;
    int wr = bn + row; if (wr >= N) wr = N - 1;
    gw[i] = W + (size_t)wr * K + ((cb ^ (row & 7)) << 3);
  }
  auto stage = [&](int buf){
    #pragma unroll
    for (int i = 0; i < 4; i++) { gload_lds16(ga[i], &As[buf][(i*256 + wv*64)*8]); ga[i] += 64; }
    #pragma unroll
    for (int i = 0; i < 2; i++) { gload_lds16(gw[i], &Ws[buf][(i*256 + wv*64)*8]); gw[i] += 64; }
  };

  f32x4 acc[2][4];
  #pragma unroll
  for (int mi = 0; mi < 2; mi++)
    #pragma unroll
    for (int nj = 0; nj < 4; nj++) acc[mi][nj] = (f32x4){0.f,0.f,0.f,0.f};

  stage(0);
  const int iters = K >> 6;
  for (int it = 0; it < iters; it++) {
    const int cur = it & 1;
    __syncthreads();
    if (it + 1 < iters) stage(cur ^ 1);
    #pragma unroll
    for (int ks = 0; ks < 2; ks++) {
      const int cb = ((ks*4 + quad) ^ (m & 7)) << 3;
      bf16x8 af[2], wf[4];
      #pragma unroll
      for (int mi = 0; mi < 2; mi++)
        af[mi] = *(const bf16x8*)(&As[cur][(wv*32 + mi*16 + m) * 64 + cb]);
      #pragma unroll
      for (int nj = 0; nj < 4; nj++)
        wf[nj] = *(const bf16x8*)(&Ws[cur][(nj*16 + m) * 64 + cb]);
      #pragma unroll
      for (int mi = 0; mi < 2; mi++)
        #pragma unroll
        for (int nj = 0; nj < 4; nj++)
          acc[mi][nj] = __builtin_amdgcn_mfma_f32_16x16x32_bf16(af[mi], wf[nj], acc[mi][nj], 0, 0, 0);
    }
  }

  #pragma unroll
  for (int mi = 0; mi < 2; mi++)
    #pragma unroll
    for (int nj = 0; nj < 4; nj++) {
      const int col = bn + nj*16 + m;
      if (col < N) {
        #pragma unroll
        for (int r = 0; r < 4; r++) {
          const int row = bm + wv*32 + mi*16 + quad*4 + r;
          if constexpr (sizeof(CT) == 2)
            C[(size_t)row * N + col] = (CT)__float2bfloat16(acc[mi][nj][r]);
          else
            C[(size_t)row * N + col] = acc[mi][nj][r];
        }
      }
    }
}

// ---- merged Wq(+fused RMSNorm/RoPE) and Wkva GEMM: one launch, K=1024 ----
// blockIdx.x<16: q path (head=x, epilogue->qb16); else kva path (f32 out).
__global__ __launch_bounds__(256, 2)
void gemm_qkva(const __hip_bfloat16* __restrict__ A, const __hip_bfloat16* __restrict__ Wqb,
               const __hip_bfloat16* __restrict__ Wkvab,
               const float* __restrict__ qw, const float* __restrict__ cosp,
               const float* __restrict__ sinp,
               __hip_bfloat16* __restrict__ qb, float* __restrict__ kva)
{
  __shared__ __hip_bfloat16 As[2][128 * 64];
  __shared__ __hip_bfloat16 Ws[2][64 * 64];
  const int K = 1024;
  const int tid = threadIdx.x;
  const int wv = tid >> 6, lane = tid & 63;
  const int m = lane & 15, quad = lane >> 4;
  const int bm = blockIdx.y * 128;
  const bool isq = blockIdx.x < 16;
  const __hip_bfloat16* W = isq ? Wqb : Wkvab;
  const int bn = isq ? blockIdx.x*64 : (blockIdx.x - 16)*64;
  const int Nw = isq ? 1024 : 144;

  const __hip_bfloat16* ga[4];
  const __hip_bfloat16* gw[2];
  #pragma unroll
  for (int i = 0; i < 4; i++) {
    const int slot = i*256 + tid;
    const int row = slot >> 3, cb = slot & 7;
    ga[i] = A + (size_t)(bm + row) * K + ((cb ^ (row & 7)) << 3);
  }
  #pragma unroll
  for (int i = 0; i < 2; i++) {
    const int slot = i*256 + tid;
    const int row = slot >> 3, cb = slot & 7;
    int wr = bn + row; if (wr >= Nw) wr = Nw - 1;
    gw[i] = W + (size_t)wr * K + ((cb ^ (row & 7)) << 3);
  }
  auto stage = [&](int buf){
    #pragma unroll
    for (int i = 0; i < 4; i++) { gload_lds16(ga[i], &As[buf][(i*256 + wv*64)*8]); ga[i] += 64; }
    #pragma unroll
    for (int i = 0; i < 2; i++) { gload_lds16(gw[i], &Ws[buf][(i*256 + wv*64)*8]); gw[i] += 64; }
  };

  f32x4 acc[2][4];
  #pragma unroll
  for (int mi = 0; mi < 2; mi++)
    #pragma unroll
    for (int nj = 0; nj < 4; nj++) acc[mi][nj] = (f32x4){0.f,0.f,0.f,0.f};

  stage(0);
  for (int it = 0; it < 16; it++) {
    const int cur = it & 1;
    __syncthreads();
    if (it < 15) stage(cur ^ 1);
    #pragma unroll
    for (int ks = 0; ks < 2; ks++) {
      const int cb = ((ks*4 + quad) ^ (m & 7)) << 3;
      bf16x8 af[2], wf[4];
      #pragma unroll
      for (int mi = 0; mi < 2; mi++)
        af[mi] = *(const bf16x8*)(&As[cur][(wv*32 + mi*16 + m) * 64 + cb]);
      #pragma unroll
      for (int nj = 0; nj < 4; nj++)
        wf[nj] = *(const bf16x8*)(&Ws[cur][(nj*16 + m) * 64 + cb]);
      #pragma unroll
      for (int mi = 0; mi < 2; mi++)
        #pragma unroll
        for (int nj = 0; nj < 4; nj++)
          acc[mi][nj] = __builtin_amdgcn_mfma_f32_16x16x32_bf16(af[mi], wf[nj], acc[mi][nj], 0, 0, 0);
    }
  }

  if (isq) {
    const int head = blockIdx.x;
    float qwv[4];
    #pragma unroll
    for (int nj = 0; nj < 4; nj++) qwv[nj] = qw[nj*16 + m];
    const int j = m & 7;
    #pragma unroll
    for (int mi = 0; mi < 2; mi++) {
      #pragma unroll
      for (int r = 0; r < 4; r++) {
        float ss = 0.f;
        #pragma unroll
        for (int nj = 0; nj < 4; nj++) { const float t = acc[mi][nj][r]; ss = fmaf(t, t, ss); }
        ss += __shfl_xor(ss, 1, 64); ss += __shfl_xor(ss, 2, 64);
        ss += __shfl_xor(ss, 4, 64); ss += __shfl_xor(ss, 8, 64);
        const float nrm = rsqrtf(ss * (1.0f/64.0f) + EPS);
        float v[4];
        #pragma unroll
        for (int nj = 0; nj < 4; nj++) v[nj] = acc[mi][nj][r] * nrm * qwv[nj];
        const int grow = bm + wv*32 + mi*16 + quad*4 + r;
        const int t = grow & (T_ - 1);
        const int b = grow >> 11;
        const float part = __shfl_xor(v[3], 8, 64);
        const float c = cosp[t*8 + j], sn = sinp[t*8 + j];
        v[3] = (m < 8) ? (v[3]*c - part*sn) : (v[3]*c + part*sn);
        __hip_bfloat16* dst = qb + ((size_t)(b*NH + head)*T_ + t)*64 + m;
        #pragma unroll
        for (int nj = 0; nj < 4; nj++) dst[nj*16] = __float2bfloat16(v[nj] * 0.125f);
      }
    }
  } else {
    #pragma unroll
    for (int mi = 0; mi < 2; mi++)
      #pragma unroll
      for (int nj = 0; nj < 4; nj++) {
        const int col = bn + nj*16 + m;
        if (col < 144) {
          #pragma unroll
          for (int r = 0; r < 4; r++) {
            const int row = bm + wv*32 + mi*16 + quad*4 + r;
            kva[(size_t)row * 144 + col] = acc[mi][nj][r];
          }
        }
      }
  }
}

// Per (b,t): RMSNorm over kv_a[:128] -> kvl16; RoPE on kv_a[128:144] -> krope16.
__global__ void prep_kv(const float* __restrict__ kva, const float* __restrict__ kw,
                        const float* __restrict__ cosp, const float* __restrict__ sinp,
                        __hip_bfloat16* __restrict__ kvl16, __hip_bfloat16* __restrict__ krope16)
{
  const int tid = threadIdx.x;   // 0..127
  const int bt = blockIdx.x;
  const int t = bt % T_;
  const float* row = kva + (size_t)bt * 144;
  const float v = row[tid];
  float s = wred_sum(v * v);
  __shared__ float red[2];
  if ((tid & 63) == 0) red[tid >> 6] = s;
  __syncthreads();
  const float total = red[0] + red[1];
  const float norm = rsqrtf(total * (1.0f/128.0f) + EPS);
  kvl16[(size_t)bt * 128 + tid] = __float2bfloat16(v * norm * kw[tid]);
  if (tid < 16) {
    const int j = tid & 7;
    const float c = cosp[t*8 + j], sn = sinp[t*8 + j];
    const float x1 = row[128 + j], x2 = row[136 + j];
    krope16[(size_t)bt * 16 + tid] = __float2bfloat16((tid < 8) ? (x1 * c - x2 * sn)
                                                               : (x2 * c + x1 * sn));
  }
}

// ---- kvb GEMM (K=128, N=1792 permuted) with fused outputs:
// col-blocks 0..11 -> knope16 row-major (pitch 768); 12..27 -> vt16 transposed.
__global__ __launch_bounds__(256, 2)
void gemm_kvb(const __hip_bfloat16* __restrict__ A, const __hip_bfloat16* __restrict__ W,
              __hip_bfloat16* __restrict__ knope, __hip_bfloat16* __restrict__ vt)
{
  __shared__ __hip_bfloat16 As[2][128 * 64];
  __shared__ __hip_bfloat16 Ws[2][64 * 64];
  const int K = 128;
  const int tid = threadIdx.x;
  const int wv = tid >> 6, lane = tid & 63;
  const int m = lane & 15, quad = lane >> 4;
  const int bm = blockIdx.y * 128, bn = blockIdx.x * 64;

  const __hip_bfloat16* ga[4];
  const __hip_bfloat16* gw[2];
  #pragma unroll
  for (int i = 0; i < 4; i++) {
    const int slot = i*256 + tid;
    const int row = slot >> 3, cb = slot & 7;
    ga[i] = A + (size_t)(bm + row) * K + ((cb ^ (row & 7)) << 3);
  }
  #pragma unroll
  for (int i = 0; i < 2; i++) {
    const int slot = i*256 + tid;
    const int row = slot >> 3, cb = slot & 7;
    gw[i] = W + (size_t)(bn + row) * K + ((cb ^ (row & 7)) << 3);
  }
  auto stage = [&](int buf){
    #pragma unroll
    for (int i = 0; i < 4; i++) { gload_lds16(ga[i], &As[buf][(i*256 + wv*64)*8]); ga[i] += 64; }
    #pragma unroll
    for (int i = 0; i < 2; i++) { gload_lds16(gw[i], &Ws[buf][(i*256 + wv*64)*8]); gw[i] += 64; }
  };

  f32x4 acc[2][4];
  #pragma unroll
  for (int mi = 0; mi < 2; mi++)
    #pragma unroll
    for (int nj = 0; nj < 4; nj++) acc[mi][nj] = (f32x4){0.f,0.f,0.f,0.f};

  stage(0);
  for (int it = 0; it < 2; it++) {
    const int cur = it & 1;
    __syncthreads();
    if (it == 0) stage(1);
    #pragma unroll
    for (int ks = 0; ks < 2; ks++) {
      const int cb = ((ks*4 + quad) ^ (m & 7)) << 3;
      bf16x8 af[2], wf[4];
      #pragma unroll
      for (int mi = 0; mi < 2; mi++)
        af[mi] = *(const bf16x8*)(&As[cur][(wv*32 + mi*16 + m) * 64 + cb]);
      #pragma unroll
      for (int nj = 0; nj < 4; nj++)
        wf[nj] = *(const bf16x8*)(&Ws[cur][(nj*16 + m) * 64 + cb]);
      #pragma unroll
      for (int mi = 0; mi < 2; mi++)
        #pragma unroll
        for (int nj = 0; nj < 4; nj++)
          acc[mi][nj] = __builtin_amdgcn_mfma_f32_16x16x32_bf16(af[mi], wf[nj], acc[mi][nj], 0, 0, 0);
    }
  }

  if (bn < 768) {
    #pragma unroll
    for (int mi = 0; mi < 2; mi++)
      #pragma unroll
      for (int nj = 0; nj < 4; nj++) {
        const int col = bn + nj*16 + m;
        #pragma unroll
        for (int r = 0; r < 4; r++) {
          const int row = bm + wv*32 + mi*16 + quad*4 + r;
          knope[(size_t)row * 768 + col] = __float2bfloat16(acc[mi][nj][r]);
        }
      }
  } else {
    // transpose 128t x 64d tile -> vt16[b,h,d,t] via LDS bounce
    __syncthreads();
    short* TL = (short*)&As[0][0];          // [64 d][pitch 136]
    #pragma unroll
    for (int mi = 0; mi < 2; mi++)
      #pragma unroll
      for (int nj = 0; nj < 4; nj++) {
        const int d = nj*16 + m;
        #pragma unroll
        for (int r = 0; r < 4; r++) {
          const int tl = wv*32 + mi*16 + quad*4 + r;
          __hip_bfloat16 hv = __float2bfloat16(acc[mi][nj][r]);
          short sv; __builtin_memcpy(&sv, &hv, 2);
          TL[d*136 + tl] = sv;
        }
      }
    __syncthreads();
    const int h = (bn - 768) >> 6;
    const int b = bm >> 11;
    const int t0 = bm & (T_ - 1);
    #pragma unroll
    for (int i = 0; i < 4; i++) {
      const int unit = i*256 + tid;        // 1024 units of 8 elems
      const int d = unit >> 4, tu = unit & 15;
      *(bf16x8*)(vt + ((size_t)(b*NH + h)*64 + d)*T_ + t0 + tu*8)
          = *(const bf16x8*)(TL + d*136 + tu*8);
    }
  }
}

// ---- softmax update for one state over a 128-key tile; produces PV A-frags ----
__device__ __forceinline__ void fa_softmax(f32x4 (&s)[8], const bool diag,
    const int k0, const int qglob, const int m, const int quad,
    float& mrun, float& lrun, f32x4 (&o)[4], bf16x8 (&a)[4])
{
  if (diag) {
    #pragma unroll
    for (int sub = 0; sub < 8; sub++)
      #pragma unroll
      for (int r = 0; r < 4; r++)
        if (k0 + sub*16 + quad*4 + r > qglob) s[sub][r] = -1e30f;
  }
  float tm = -3.0e38f;
  #pragma unroll
  for (int sub = 0; sub < 8; sub++)
    #pragma unroll
    for (int r = 0; r < 4; r++) tm = fmaxf(tm, s[sub][r]);
  tm = fmaxf(tm, __shfl_xor(tm, 16, 64));
  tm = fmaxf(tm, __shfl_xor(tm, 32, 64));
  const float mn = fmaxf(mrun, tm);
  const float alpha = __expf(mrun - mn);
  float rs = 0.f;
  float p[8][4];
  #pragma unroll
  for (int sub = 0; sub < 8; sub++)
    #pragma unroll
    for (int r = 0; r < 4; r++) {
      const float e = __expf(s[sub][r] - mn);
      p[sub][r] = e; rs += e;
    }
  rs += __shfl_xor(rs, 16, 64);
  rs += __shfl_xor(rs, 32, 64);
  lrun = lrun * alpha + rs;
  mrun = mn;

  unsigned u[8][2];
  #pragma unroll
  for (int sub = 0; sub < 8; sub++) {
    u[sub][0] = pack_bf16(p[sub][0], p[sub][1]);
    u[sub][1] = pack_bf16(p[sub][2], p[sub][3]);
  }
  // shuffle BOTH sub-words, select with DEST quad after (source-lane quad differs)
  #pragma unroll
  for (int c = 0; c < 4; c++) {
    union { int i[4]; bf16x8 v; } au;
    #pragma unroll
    for (int w4 = 0; w4 < 4; w4++) {
      const int src = (((2*quad + (w4 >> 1)) & 3) << 4) | m;
      const int lo = __shfl((int)u[c*2][w4 & 1], src, 64);
      const int hi = __shfl((int)u[c*2+1][w4 & 1], src, 64);
      au.i[w4] = (quad & 2) ? hi : lo;
    }
    a[c] = au.v;
  }

  float al[4];
  #pragma unroll
  for (int r = 0; r < 4; r++) al[r] = __shfl(alpha, (quad << 2) | r, 64);
  #pragma unroll
  for (int vs = 0; vs < 4; vs++)
    #pragma unroll
    for (int r = 0; r < 4; r++) o[vs][r] *= al[r];
}

__device__ __forceinline__ void fa_store(float lrun, f32x4 (&oacc)[4],
    const int b, const int qrow0, const int h, const int m, const int quad,
    __hip_bfloat16* __restrict__ aout)
{
  float lr[4];
  #pragma unroll
  for (int r = 0; r < 4; r++) lr[r] = __shfl(lrun, (quad << 2) | r, 64);
  #pragma unroll
  for (int vs = 0; vs < 4; vs++)
    #pragma unroll
    for (int r = 0; r < 4; r++)
      aout[(size_t)(b*T_ + qrow0 + quad*4 + r) * 1024 + h*64 + vs*16 + m]
          = __float2bfloat16(oacc[vs][r] / lr[r]);
}

// Pair-balanced MFMA flash attention, BK=128, double-buffered LDS staging.
__global__ __launch_bounds__(256, 2)
void attn_pair2(const __hip_bfloat16* __restrict__ qb,
                const __hip_bfloat16* __restrict__ knope,
                const __hip_bfloat16* __restrict__ krope16,
                const __hip_bfloat16* __restrict__ vt16,
                __hip_bfloat16* __restrict__ aout)
{
  __shared__ __hip_bfloat16 SL[32768];   // K: [buf][128][64] @0/8192; V: [buf][64][128] @16384/24576
  const int tid = threadIdx.x;
  const int wv = tid >> 6, lane = tid & 63;
  const int m = lane & 15, quad = lane >> 4;
  const int ta = blockIdx.x;            // 0..15
  const int tb = 31 - ta;               // 16..31
  const int bh = blockIdx.y;
  const int b = bh >> 4, h = bh & 15;
  const int qbaseA = ta*64 + wv*16;
  const int qbaseB = tb*64 + wv*16;
  const int ntA = (ta + 2) >> 1;
  const int ntB = (tb + 2) >> 1;

  const __hip_bfloat16* qra = qb + ((size_t)bh*T_ + qbaseA + m)*64 + quad*8;
  const bf16x8 qA0 = *(const bf16x8*)qra, qA1 = *(const bf16x8*)(qra + 32);
  const __hip_bfloat16* qrb = qb + ((size_t)bh*T_ + qbaseB + m)*64 + quad*8;
  const bf16x8 qB0 = *(const bf16x8*)qrb, qB1 = *(const bf16x8*)(qrb + 32);

  const __hip_bfloat16* pK[4]; size_t iK[4];
  const __hip_bfloat16* pV[4];
  #pragma unroll
  for (int i = 0; i < 4; i++) {
    const int slot = i*256 + tid;
    const int krow = slot >> 3;
    const int kde = (slot & 7) ^ (krow & 7);
    if (kde < 6) { pK[i] = knope + (size_t)(b*T_ + krow)*768 + h*48 + kde*8; iK[i] = (size_t)128*768; }
    else         { pK[i] = krope16 + (size_t)(b*T_ + krow)*16 + (kde-6)*8;   iK[i] = (size_t)128*16; }
    const int vd = slot >> 4;
    const int vde = (slot & 15) ^ (vd & 7);
    pV[i] = vt16 + ((size_t)bh*64 + vd)*T_ + vde*8;
  }

  auto stage = [&](int buf){
    #pragma unroll
    for (int i = 0; i < 4; i++) {
      gload_lds16(pK[i], SL + buf*8192 + (i*256 + wv*64)*8);
      gload_lds16(pV[i], SL + 16384 + buf*8192 + (i*256 + wv*64)*8);
      pK[i] += iK[i]; pV[i] += 128;
    }
  };

  f32x4 oA[4], oB[4];
  #pragma unroll
  for (int vs = 0; vs < 4; vs++) { oA[vs] = (f32x4){0.f,0.f,0.f,0.f}; oB[vs] = (f32x4){0.f,0.f,0.f,0.f}; }
  float mA = -3.0e38f, lA = 0.f, mB = -3.0e38f, lB = 0.f;

  const int sw0 = quad ^ (m & 7);
  stage(0);

  for (int kt = 0; kt < ntB; kt++) {
    const int cur = kt & 1;
    __syncthreads();
    const __hip_bfloat16* Kc = SL + cur*8192;
    const __hip_bfloat16* Vc = SL + 16384 + cur*8192;
    const bool doA = (kt < ntA);

    f32x4 sA[8], sB[8];
    #pragma unroll
    for (int sub = 0; sub < 8; sub++) {
      const bf16x8 kf0 = *(const bf16x8*)(Kc + (sub*16 + m)*64 + sw0*8);
      const bf16x8 kf1 = *(const bf16x8*)(Kc + (sub*16 + m)*64 + (sw0^4)*8);
      f32x4 z = (f32x4){0.f,0.f,0.f,0.f};
      z = __builtin_amdgcn_mfma_f32_16x16x32_bf16(kf0, qB0, z, 0, 0, 0);
      z = __builtin_amdgcn_mfma_f32_16x16x32_bf16(kf1, qB1, z, 0, 0, 0);
      sB[sub] = z;
      if (doA) {
        f32x4 y = (f32x4){0.f,0.f,0.f,0.f};
        y = __builtin_amdgcn_mfma_f32_16x16x32_bf16(kf0, qA0, y, 0, 0, 0);
        y = __builtin_amdgcn_mfma_f32_16x16x32_bf16(kf1, qA1, y, 0, 0, 0);
        sA[sub] = y;
      }
    }

    if (kt + 1 < ntB) stage(cur ^ 1);

    bf16x8 aA[4], aB[4];
    fa_softmax(sB, kt == ntB-1, kt*128, qbaseB + m, m, quad, mB, lB, oB, aB);
    if (doA) fa_softmax(sA, kt == ntA-1, kt*128, qbaseA + m, m, quad, mA, lA, oA, aA);

    #pragma unroll
    for (int vs = 0; vs < 4; vs++) {
      #pragma unroll
      for (int c = 0; c < 4; c++) {
        const bf16x8 vf = *(const bf16x8*)(Vc + (vs*16 + m)*128 + (((c*4 + quad) ^ (m & 7)) << 3));
        oB[vs] = __builtin_amdgcn_mfma_f32_16x16x32_bf16(aB[c], vf, oB[vs], 0, 0, 0);
        if (doA) oA[vs] = __builtin_amdgcn_mfma_f32_16x16x32_bf16(aA[c], vf, oA[vs], 0, 0, 0);
      }
    }
  }

  fa_store(lA, oA, b, qbaseA, h, m, quad, aout);
  fa_store(lB, oB, b, qbaseB, h, m, quad, aout);
}

extern "C" void kernel_launch(void* const* d_in, const int* in_sizes, int n_in,
                              void* d_out, int out_size, void* d_ws, size_t ws_size,
                              hipStream_t stream)
{
  const float* x    = (const float*)d_in[0];
  const float* cosp = (const float*)d_in[1];
  const float* sinp = (const float*)d_in[2];
  const float* Wq   = (const float*)d_in[3];
  const float* qw   = (const float*)d_in[4];
  const float* Wkva = (const float*)d_in[5];
  const float* kw   = (const float*)d_in[6];
  const float* Wkvb = (const float*)d_in[7];
  const float* Wo   = (const float*)d_in[8];
  float* out = (float*)d_out;

  float* kva = (float*)d_ws;                                  //   589,824 f
  __hip_bfloat16* xb16    = (__hip_bfloat16*)(kva + 589824);  // 4,194,304
  __hip_bfloat16* knope16 = xb16 + 4194304;                   // 3,145,728
  __hip_bfloat16* kvl16   = knope16 + 3145728;                //   524,288
  __hip_bfloat16* qb16    = kvl16 + 524288;                   // 4,194,304
  __hip_bfloat16* vt16    = qb16 + 4194304;                   // 4,194,304
  __hip_bfloat16* krope16 = vt16 + 4194304;                   //    65,536
  __hip_bfloat16* Wqb     = krope16 + 65536;                  // 1,048,576
  __hip_bfloat16* Wkvab   = Wqb + 1048576;                    //   147,456
  __hip_bfloat16* Wkvbb   = Wkvab + 147456;                   //   229,376
  __hip_bfloat16* Wob     = Wkvbb + 229376;                   // 1,048,576
  __hip_bfloat16* ab16    = Wob + 1048576;                    // 4,194,304

  const int M = B_ * T_;   // 4096

  cvt5<<<6512, 256, 0, stream>>>(x, Wq, Wkva, Wkvb, Wo, xb16, Wqb, Wkvab, Wkvbb, Wob);
  gemm_qkva<<<dim3(19, 32), 256, 0, stream>>>(xb16, Wqb, Wkvab, qw, cosp, sinp, qb16, kva);
  prep_kv<<<M, 128, 0, stream>>>(kva, kw, cosp, sinp, kvl16, krope16);
  gemm_kvb<<<dim3(28, 32), 256, 0, stream>>>(kvl16, Wkvbb, knope16, vt16);
  attn_pair2<<<dim3(16, B_ * NH), 256, 0, stream>>>(qb16, knope16, krope16, vt16, ab16);
  gemm_bt64<float><<<dim3(16, 32), 256, 0, stream>>>(ab16, Wob, out, M, 1024, 1024);
}